// Round 1
// baseline (359.695 us; speedup 1.0000x reference)
//
#include <hip/hip_runtime.h>

static constexpr int T_LEN = 1024;
static constexpr int KTAG = 24;
static constexpr int MAT = 576;      // 24*24
static constexpr int START_TAG = 22;
static constexpr int END_TAG = 23;
static constexpr int BATCH = 128;

__device__ __forceinline__ float fexp2(float x) { return __builtin_amdgcn_exp2f(x); }
__device__ __forceinline__ float flog2(float x) { return __builtin_amdgcn_logf(x); }

// One wave per batch chain. Lane = h*32 + j: h = i-half (0: i in [0,12), 1: [12,24)),
// j = output column (j<24 active). Works in base-2 log units (scores pre-scaled by
// log2(e) via fma), stale-by-one-step max M keeps the 6-stage max butterfly off the
// per-step critical path.
__global__ __launch_bounds__(64) void crf_chain_kernel(
    const float* __restrict__ scores, const int* __restrict__ lengths,
    float* __restrict__ acc)
{
  const int b = blockIdx.x;
  const int lane = threadIdx.x;
  const int h = lane >> 5;
  const int j = lane & 31;
  const int jj = j < KTAG ? j : (KTAG - 1);
  const bool act = (j < KTAG);
  const float C = 1.4426950408889634f;   // log2(e)
  const float LN2 = 0.6931471805599453f;

  const int len = lengths[b];
  const float* base = scores + (size_t)b * T_LEN * MAT;
  const int lbase = h * 12 * KTAG + jj;  // row h*12, col jj of the 24x24 matrix

  // prev'[j] = scores[b,0,START,j] * log2e  (base-2 units)
  float pcur = base[START_TAG * KTAG + jj] * C;
  if (!act) pcur = -1e30f;

  // fresh max over all columns
  float M = pcur;
  #pragma unroll
  for (int off = 1; off < 64; off <<= 1)
    M = fmaxf(M, __shfl_xor(M, off, 64));
  float Mnext = M;

  // pm[k] = prev'[h*12+k] - M  (this lane's 12 i-values, max-shifted)
  float pm[12];
  #pragma unroll
  for (int k = 0; k < 12; ++k)
    pm[k] = __shfl(pcur, h * 12 + k, 64) - M;

  float svA[12], svB[12];

  auto LOAD = [&](float (&buf)[12], int t) {
    const float* p = base + (size_t)t * MAT + lbase;
    #pragma unroll
    for (int k = 0; k < 12; ++k) buf[k] = p[k * KTAG];  // s[h*12+k][jj] of step t
  };

  auto STEP = [&](float (&buf)[12]) {
    float e[12];
    #pragma unroll
    for (int k = 0; k < 12; ++k)
      e[k] = fexp2(fmaf(buf[k], C, pm[k]));   // 2^(s' + p' - M)
    float t0 = e[0] + e[1],  t1 = e[2] + e[3],  t2 = e[4] + e[5];
    float t3 = e[6] + e[7],  t4 = e[8] + e[9],  t5 = e[10] + e[11];
    float u0 = t0 + t1, u1 = t2 + t3, u2 = t4 + t5;
    float s = (u0 + u1) + u2;
    float tot = s + __shfl_xor(s, 32, 64);    // combine i-halves
    float newp = M + flog2(tot);
    newp = act ? newp : -1e30f;
    pcur = newp;
    M = Mnext;                                // stale-by-one max for next step
    #pragma unroll
    for (int k = 0; k < 12; ++k)
      pm[k] = __shfl(newp, h * 12 + k, 64) - M;
    // butterfly for the step after next (off critical path)
    float bm = newp;
    #pragma unroll
    for (int off = 1; off < 64; off <<= 1)
      bm = fmaxf(bm, __shfl_xor(bm, off, 64));
    Mnext = bm;
  };

  if (len >= 2) {
    const int tmax = len - 1;
    LOAD(svA, 1);
    LOAD(svB, 2 <= tmax ? 2 : tmax);
    int t = 1;
    while (t + 1 <= tmax) {
      STEP(svA);
      { int tn = t + 2; LOAD(svA, tn <= tmax ? tn : tmax); }
      STEP(svB);
      { int tn = t + 3; LOAD(svB, tn <= tmax ? tn : tmax); }
      t += 2;
    }
    if (t <= tmax) STEP(svA);
  }

  float res = __shfl(pcur, END_TAG, 64) * LN2;  // back to natural-log units
  if (lane == 0) atomicAdd(acc, res);
}

// gold = sum over (b, t<len) of scores[b,t].flat[targets[b,t]]; accumulated NEGATED.
__global__ __launch_bounds__(256) void gold_kernel(
    const float* __restrict__ scores, const int* __restrict__ targets,
    const int* __restrict__ lengths, float* __restrict__ acc)
{
  const int idx = blockIdx.x * blockDim.x + threadIdx.x;   // b*1024 + t
  const int b = idx >> 10;
  const int t = idx & (T_LEN - 1);
  float v = 0.f;
  if (t < lengths[b]) v = scores[(size_t)idx * MAT + targets[idx]];
  #pragma unroll
  for (int off = 1; off < 64; off <<= 1) v += __shfl_xor(v, off, 64);
  if ((threadIdx.x & 63) == 0) atomicAdd(acc, -v);
}

__global__ void finalize_kernel(const float* __restrict__ acc, float* __restrict__ out) {
  out[0] = acc[0] * (1.0f / (float)BATCH);
}

extern "C" void kernel_launch(void* const* d_in, const int* in_sizes, int n_in,
                              void* d_out, int out_size, void* d_ws, size_t ws_size,
                              hipStream_t stream) {
  const float* scores = (const float*)d_in[0];
  const int* targets  = (const int*)d_in[1];
  const int* lengths  = (const int*)d_in[2];
  float* out = (float*)d_out;
  float* acc = (float*)d_ws;

  hipMemsetAsync(acc, 0, sizeof(float), stream);
  gold_kernel<<<BATCH * T_LEN / 256, 256, 0, stream>>>(scores, targets, lengths, acc);
  crf_chain_kernel<<<BATCH, 64, 0, stream>>>(scores, lengths, acc);
  finalize_kernel<<<1, 1, 0, stream>>>(acc, out);
}

// Round 3
// 232.843 us; speedup vs baseline: 1.5448x; 1.5448x over previous
//
#include <hip/hip_runtime.h>

static constexpr int T_LEN = 1024;
static constexpr int KTAG = 24;
static constexpr int MAT = 576;      // 24*24
static constexpr int START_TAG = 22;
static constexpr int END_TAG = 23;
static constexpr int BATCH = 128;

__device__ __forceinline__ float fexp2(float x) { return __builtin_amdgcn_exp2f(x); }
__device__ __forceinline__ float flog2(float x) { return __builtin_amdgcn_logf(x); }

// Linear-space CRF chain step. State: p[tag] = E + log2(tau[tag]), tau in fp32,
// E wave-uniform int. Per step: tau_new[j] = (sum_i tau[i] * 2^(s'[i][j])) * 2^(-d),
// E += d, with d = exponent field of tau[0] (readfirstlane on the BIT PATTERN —
// the float overload trap was R1's inf). The exps depend only on loaded scores
// -> off the sequential critical path.
// DIR=0: forward (reduce over rows i, strided loads). DIR=1: backward (reduce over
// cols j, contiguous dwordx4 loads). Returns E.
template<int DIR>
__device__ __forceinline__ int run_chain(const float* __restrict__ base, int len, int n,
                                         volatile float* __restrict__ tau,
                                         int lane, int h, int jj)
{
  const float C = 1.4426950408889634f;   // log2(e)
  int E = 0;
  float ref = 1.0f;

  float A[12], B[12], Cb[12];

  auto LOAD = [&](float (&buf)[12], int i) {
    if (DIR == 0) {
      // t = 1 + i; lane (h, col jj) needs s[h*12+k][jj], stride 24 floats
      const float* p = base + (size_t)(1 + i) * MAT + h * 12 * KTAG + jj;
      #pragma unroll
      for (int k = 0; k < 12; ++k) buf[k] = p[k * KTAG];
    } else {
      // t = len-1-i; lane (h, row jj) needs s[jj][h*12+k], contiguous 48B
      const float4* p = (const float4*)(base + (size_t)(len - 1 - i) * MAT + jj * KTAG + h * 12);
      float4 x = p[0], y = p[1], z = p[2];
      buf[0] = x.x; buf[1] = x.y; buf[2]  = x.z; buf[3]  = x.w;
      buf[4] = y.x; buf[5] = y.y; buf[6]  = y.z; buf[7]  = y.w;
      buf[8] = z.x; buf[9] = z.y; buf[10] = z.z; buf[11] = z.w;
    }
  };

  auto STEP = [&](const float (&buf)[12]) {
    // rescale: d = exponent of last step's tau[0] (SALU, off the fma chain)
    int rb = __builtin_amdgcn_readfirstlane(__float_as_int(ref));
    int d = ((rb >> 23) & 255) - 127;
    float sc = __int_as_float((127 - d) << 23);   // 2^(-d)
    E += d;
    float w[12];
    #pragma unroll
    for (int k = 0; k < 12; ++k) w[k] = fexp2(buf[k] * C);
    const float4* tp = (const float4*)(&tau[h * 12]);
    float4 t0 = tp[0], t1 = tp[1], t2 = tp[2];
    float a0 = t0.x * w[0], a1 = t0.y * w[1], a2 = t0.z * w[2], a3 = t0.w * w[3];
    a0 = fmaf(t1.x, w[4],  a0); a1 = fmaf(t1.y, w[5],  a1);
    a2 = fmaf(t1.z, w[6],  a2); a3 = fmaf(t1.w, w[7],  a3);
    a0 = fmaf(t2.x, w[8],  a0); a1 = fmaf(t2.y, w[9],  a1);
    a2 = fmaf(t2.z, w[10], a2); a3 = fmaf(t2.w, w[11], a3);
    float part = (a0 + a1) + (a2 + a3);
    float tot = part + __shfl_xor(part, 32, 64);   // combine i-halves
    float tn = tot * sc;
    if (lane < KTAG) tau[lane] = tn;               // lanes 0..23 (h=0) publish
    ref = tn;
  };

  if (n > 0) {
    LOAD(A, 0);
    LOAD(B, n > 1 ? 1 : 0);
    LOAD(Cb, n > 2 ? 2 : 0);
    int i = 0;
    while (i + 3 <= n) {
      STEP(A);  { int ii = i + 3; LOAD(A,  ii < n ? ii : n - 1); }
      STEP(B);  { int ii = i + 4; LOAD(B,  ii < n ? ii : n - 1); }
      STEP(Cb); { int ii = i + 5; LOAD(Cb, ii < n ? ii : n - 1); }
      i += 3;
    }
    if (i < n)     STEP(A);
    if (i + 1 < n) STEP(B);
  }
  return E;
}

// One block per batch: wave 0 = forward chain over t=1..m, wave 1 = backward chain
// over t=len-1..m+1 (starting from e_END). Combine: result = (Ef+Eg+log2(dot))·ln2.
__global__ __launch_bounds__(128) void crf_fb_kernel(
    const float* __restrict__ scores, const int* __restrict__ lengths,
    float* __restrict__ acc)
{
  __shared__ float sm[2][32];
  __shared__ int smE[2];
  const int b = blockIdx.x;
  const int tid = threadIdx.x;
  const int wid = tid >> 6;        // 0 = fwd, 1 = bwd
  const int lane = tid & 63;
  const int h = lane >> 5;
  const int j = lane & 31;
  const int jj = j < KTAG ? j : KTAG - 1;
  const float C = 1.4426950408889634f;
  const int len = lengths[b];
  const float* base = scores + (size_t)b * T_LEN * MAT;
  const int m = len >> 1;
  volatile float* tau = sm[wid];

  int E;
  if (wid == 0) {
    if (lane < KTAG) tau[lane] = fexp2(base[START_TAG * KTAG + lane] * C);
    E = run_chain<0>(base, len, m, tau, lane, h, jj);
  } else {
    if (lane < KTAG) tau[lane] = (lane == END_TAG) ? 1.0f : 0.0f;
    E = run_chain<1>(base, len, len - 1 - m, tau, lane, h, jj);
  }
  if (lane == 0) smE[wid] = E;
  __syncthreads();
  if (wid == 0) {
    float v = (lane < KTAG) ? sm[0][lane] * sm[1][lane] : 0.0f;
    #pragma unroll
    for (int off = 1; off < 32; off <<= 1) v += __shfl_xor(v, off, 64);
    if (lane == 0) {
      float res = ((float)(smE[0] + smE[1]) + flog2(v)) * 0.6931471805599453f;
      atomicAdd(acc, res);
    }
  }
}

// gold = sum over (b, t<len) of scores[b,t].flat[targets[b,t]]; accumulated NEGATED.
__global__ __launch_bounds__(256) void gold_kernel(
    const float* __restrict__ scores, const int* __restrict__ targets,
    const int* __restrict__ lengths, float* __restrict__ acc)
{
  const int idx = blockIdx.x * blockDim.x + threadIdx.x;   // b*1024 + t
  const int b = idx >> 10;
  const int t = idx & (T_LEN - 1);
  float v = 0.f;
  if (t < lengths[b]) v = scores[(size_t)idx * MAT + targets[idx]];
  #pragma unroll
  for (int off = 1; off < 64; off <<= 1) v += __shfl_xor(v, off, 64);
  if ((threadIdx.x & 63) == 0) atomicAdd(acc, -v);
}

__global__ void finalize_kernel(const float* __restrict__ acc, float* __restrict__ out) {
  out[0] = acc[0] * (1.0f / (float)BATCH);
}

extern "C" void kernel_launch(void* const* d_in, const int* in_sizes, int n_in,
                              void* d_out, int out_size, void* d_ws, size_t ws_size,
                              hipStream_t stream) {
  const float* scores = (const float*)d_in[0];
  const int* targets  = (const int*)d_in[1];
  const int* lengths  = (const int*)d_in[2];
  float* out = (float*)d_out;
  float* acc = (float*)d_ws;

  hipMemsetAsync(acc, 0, sizeof(float), stream);
  gold_kernel<<<BATCH * T_LEN / 256, 256, 0, stream>>>(scores, targets, lengths, acc);
  crf_fb_kernel<<<BATCH, 128, 0, stream>>>(scores, lengths, acc);
  finalize_kernel<<<1, 1, 0, stream>>>(acc, out);
}

// Round 4
// 154.402 us; speedup vs baseline: 2.3296x; 1.5080x over previous
//
#include <hip/hip_runtime.h>

static constexpr int T_LEN = 1024;
static constexpr int KTAG = 24;
static constexpr int MAT = 576;      // 24*24
static constexpr int START_TAG = 22;
static constexpr int END_TAG = 23;
static constexpr int BATCH = 128;
static constexpr int CHUNK = 32;     // time steps per chunk
static constexpr int NCHUNK = 32;    // (T_LEN-1)/CHUNK rounded up

__device__ __forceinline__ float fexp2(float x) { return __builtin_amdgcn_exp2f(x); }
__device__ __forceinline__ float flog2(float x) { return __builtin_amdgcn_logf(x); }

static constexpr float LOG2E = 1.4426950408889634f;
static constexpr float LN2   = 0.6931471805599453f;

// ---------------------------------------------------------------------------
// Phase A: per (batch, chunk) wave computes P = prod_{t in chunk, t<len} W_t,
// W_t[i][j] = 2^(s[t][i][j]*log2e), in fp32 with per-matmul power-of-2 rescale.
// M layout: every lane holds a full ROW jj (24 regs, replicated across halves);
// lane (h,jj) computes output columns h*12..h*12+11; re-replicate via shfl_xor.
// W_t staged in per-wave LDS, read as wave-uniform broadcasts (2 addrs/instr).
// ---------------------------------------------------------------------------
__global__ __launch_bounds__(256) void chunkprod_kernel(
    const float* __restrict__ scores, const int* __restrict__ lengths,
    float* __restrict__ wsP, int* __restrict__ wsE)
{
  __shared__ float wlds[4][2][600];   // [wave][dbuf][576 used]
  const int widx = threadIdx.x >> 6;
  const int lane = threadIdx.x & 63;
  const int w = blockIdx.x * 4 + widx;
  const int b = w >> 5;
  const int c = w & (NCHUNK - 1);
  const int len = lengths[b];
  const int t0 = 1 + c * CHUNK;
  if (t0 >= len) return;             // whole-wave exit; phase B never reads this slot
  const int nsteps = min(CHUNK, len - t0);
  const int h = lane >> 5;
  const int j = lane & 31;
  const int jj = j < KTAG ? j : KTAG - 1;
  const int ll = lane < 48 ? lane : 47;
  const float* sb = scores + (size_t)b * T_LEN * MAT;

  // M = W_{t0}: lane loads its full row jj (both halves load same row; L1 absorbs)
  float M[24];
  {
    const float4* rp = (const float4*)(sb + (size_t)t0 * MAT + jj * KTAG);
    float tmp[24];
    #pragma unroll
    for (int q = 0; q < 6; ++q) {
      float4 v = rp[q];
      tmp[q*4+0] = v.x; tmp[q*4+1] = v.y; tmp[q*4+2] = v.z; tmp[q*4+3] = v.w;
    }
    #pragma unroll
    for (int k = 0; k < 24; ++k) M[k] = fexp2(tmp[k] * LOG2E);
  }

  int E = 0;
  float4 R0, R1, R2;

  auto LOADW = [&](int step) {       // raw scores for W_{t0+step} -> R0..R2
    int t = t0 + step;
    int tc = t < len ? t : len - 1;  // clamp: prefetch beyond chunk/len never used
    const float4* p = (const float4*)(sb + (size_t)tc * MAT + ll * 12);
    R0 = p[0]; R1 = p[1]; R2 = p[2];
  };
  auto STAGE = [&](int buf) {        // exp + write 12 floats to LDS (lanes 0..47)
    if (lane < 48) {
      float v[12] = {R0.x,R0.y,R0.z,R0.w, R1.x,R1.y,R1.z,R1.w, R2.x,R2.y,R2.z,R2.w};
      float e[12];
      #pragma unroll
      for (int k = 0; k < 12; ++k) e[k] = fexp2(v[k] * LOG2E);
      float4* d4 = (float4*)&wlds[widx][buf][ll * 12];
      d4[0] = make_float4(e[0], e[1], e[2],  e[3]);
      d4[1] = make_float4(e[4], e[5], e[6],  e[7]);
      d4[2] = make_float4(e[8], e[9], e[10], e[11]);
    }
  };
  auto MATMUL = [&](int buf) {       // M <- M * W(LDS[buf]), rescale, re-replicate
    float acc[12];
    #pragma unroll
    for (int k = 0; k < 12; ++k) acc[k] = 0.f;
    const float* wl = &wlds[widx][buf][h * 12];
    #pragma unroll
    for (int i = 0; i < 24; ++i) {
      const float4* q = (const float4*)(wl + i * KTAG);   // broadcast reads
      float4 q0 = q[0], q1 = q[1], q2 = q[2];
      float mi = M[i];
      acc[0] = fmaf(mi, q0.x, acc[0]);  acc[1] = fmaf(mi, q0.y, acc[1]);
      acc[2] = fmaf(mi, q0.z, acc[2]);  acc[3] = fmaf(mi, q0.w, acc[3]);
      acc[4] = fmaf(mi, q1.x, acc[4]);  acc[5] = fmaf(mi, q1.y, acc[5]);
      acc[6] = fmaf(mi, q1.z, acc[6]);  acc[7] = fmaf(mi, q1.w, acc[7]);
      acc[8] = fmaf(mi, q2.x, acc[8]);  acc[9] = fmaf(mi, q2.y, acc[9]);
      acc[10] = fmaf(mi, q2.z, acc[10]); acc[11] = fmaf(mi, q2.w, acc[11]);
    }
    int rb = __builtin_amdgcn_readfirstlane(__float_as_int(acc[0])); // M_new[0][0]
    int d = ((rb >> 23) & 255) - 127;
    E += d;
    float sc = __int_as_float((127 - d) << 23);
    #pragma unroll
    for (int k = 0; k < 12; ++k) acc[k] *= sc;
    #pragma unroll
    for (int k = 0; k < 12; ++k) {
      float o = __shfl_xor(acc[k], 32, 64);
      M[k]      = h ? o      : acc[k];
      M[12 + k] = h ? acc[k] : o;
    }
  };

  if (nsteps > 1) {
    LOADW(1); STAGE(0);
    LOADW(2);
    for (int s = 1; s < nsteps; ++s) {
      MATMUL((s - 1) & 1);
      if (s + 1 < nsteps) { STAGE(s & 1); LOADW(s + 2); }
    }
  }

  if (lane < KTAG) {                 // h=0 lanes store row jj contiguously
    float4* d4 = (float4*)(wsP + (size_t)(b * NCHUNK + c) * MAT + lane * KTAG);
    d4[0] = make_float4(M[0],  M[1],  M[2],  M[3]);
    d4[1] = make_float4(M[4],  M[5],  M[6],  M[7]);
    d4[2] = make_float4(M[8],  M[9],  M[10], M[11]);
    d4[3] = make_float4(M[12], M[13], M[14], M[15]);
    d4[4] = make_float4(M[16], M[17], M[18], M[19]);
    d4[5] = make_float4(M[20], M[21], M[22], M[23]);
  }
  if (lane == 0) wsE[b * NCHUNK + c] = E;
}

// ---------------------------------------------------------------------------
// Phase B: one wave per batch folds chunk matrices into v0 (<=32 matvecs).
// v_new[jcol] = sum_i v[i] * P[i][jcol]; lane (h,jj) reduces i in h*12..h*12+11.
// ---------------------------------------------------------------------------
__global__ __launch_bounds__(64) void chainvec_kernel(
    const float* __restrict__ scores, const float* __restrict__ wsP,
    const int* __restrict__ wsE, const int* __restrict__ lengths,
    float* __restrict__ acc)
{
  __shared__ float tau_s[32];
  volatile float* tau = tau_s;
  const int b = blockIdx.x;
  const int lane = threadIdx.x;
  const int h = lane >> 5;
  const int j = lane & 31;
  const int jj = j < KTAG ? j : KTAG - 1;
  const int len = lengths[b];
  const int nc = (len + 30) >> 5;    // ceil((len-1)/32)

  if (lane < KTAG)
    tau[lane] = fexp2(scores[(size_t)b * T_LEN * MAT + START_TAG * KTAG + lane] * LOG2E);

  int E = 0;
  float wa[12], wb[12];

  auto LOADV = [&](float (&buf)[12], int c) {
    const float* p = wsP + (size_t)(b * NCHUNK + c) * MAT + (h * 12) * KTAG + jj;
    #pragma unroll
    for (int k = 0; k < 12; ++k) buf[k] = p[k * KTAG];
  };
  auto STEPV = [&](const float (&buf)[12], int c) {
    int ec = wsE[b * NCHUNK + c];
    const float4* tp = (const float4*)((const float*)&tau_s[h * 12]);
    float4 t0 = tp[0], t1 = tp[1], t2 = tp[2];
    float a0 = t0.x * buf[0], a1 = t0.y * buf[1], a2 = t0.z * buf[2], a3 = t0.w * buf[3];
    a0 = fmaf(t1.x, buf[4],  a0); a1 = fmaf(t1.y, buf[5],  a1);
    a2 = fmaf(t1.z, buf[6],  a2); a3 = fmaf(t1.w, buf[7],  a3);
    a0 = fmaf(t2.x, buf[8],  a0); a1 = fmaf(t2.y, buf[9],  a1);
    a2 = fmaf(t2.z, buf[10], a2); a3 = fmaf(t2.w, buf[11], a3);
    float part = (a0 + a1) + (a2 + a3);
    float tot = part + __shfl_xor(part, 32, 64);
    int rb = __builtin_amdgcn_readfirstlane(__float_as_int(tot));
    int d = ((rb >> 23) & 255) - 127;
    E += d + ec;
    float sc = __int_as_float((127 - d) << 23);
    if (lane < KTAG) tau[lane] = tot * sc;
  };

  if (nc > 0) {
    LOADV(wa, 0);
    LOADV(wb, nc > 1 ? 1 : 0);
    int c = 0;
    while (c + 1 < nc) {
      STEPV(wa, c);     { int n = c + 2; LOADV(wa, n < nc ? n : nc - 1); }
      STEPV(wb, c + 1); { int n = c + 3; LOADV(wb, n < nc ? n : nc - 1); }
      c += 2;
    }
    if (c < nc) STEPV(wa, c);
  }

  if (lane == 0) {
    float res = ((float)E + flog2(tau[END_TAG])) * LN2;
    atomicAdd(acc, res);
  }
}

// ---------------------------------------------------------------------------
// Fallback sequential FB kernel (R2, verified) — used only if ws_size is small.
// ---------------------------------------------------------------------------
template<int DIR>
__device__ __forceinline__ int run_chain(const float* __restrict__ base, int len, int n,
                                         volatile float* __restrict__ tau,
                                         int lane, int h, int jj)
{
  int E = 0;
  float ref = 1.0f;
  float A[12], B[12], Cb[12];
  auto LOAD = [&](float (&buf)[12], int i) {
    if (DIR == 0) {
      const float* p = base + (size_t)(1 + i) * MAT + h * 12 * KTAG + jj;
      #pragma unroll
      for (int k = 0; k < 12; ++k) buf[k] = p[k * KTAG];
    } else {
      const float4* p = (const float4*)(base + (size_t)(len - 1 - i) * MAT + jj * KTAG + h * 12);
      float4 x = p[0], y = p[1], z = p[2];
      buf[0]=x.x; buf[1]=x.y; buf[2]=x.z; buf[3]=x.w;
      buf[4]=y.x; buf[5]=y.y; buf[6]=y.z; buf[7]=y.w;
      buf[8]=z.x; buf[9]=z.y; buf[10]=z.z; buf[11]=z.w;
    }
  };
  auto STEP = [&](const float (&buf)[12]) {
    int rb = __builtin_amdgcn_readfirstlane(__float_as_int(ref));
    int d = ((rb >> 23) & 255) - 127;
    float sc = __int_as_float((127 - d) << 23);
    E += d;
    float w[12];
    #pragma unroll
    for (int k = 0; k < 12; ++k) w[k] = fexp2(buf[k] * LOG2E);
    const float4* tp = (const float4*)((const float*)&tau[h * 12]);
    float4 t0 = tp[0], t1 = tp[1], t2 = tp[2];
    float a0 = t0.x*w[0], a1 = t0.y*w[1], a2 = t0.z*w[2], a3 = t0.w*w[3];
    a0 = fmaf(t1.x, w[4],  a0); a1 = fmaf(t1.y, w[5],  a1);
    a2 = fmaf(t1.z, w[6],  a2); a3 = fmaf(t1.w, w[7],  a3);
    a0 = fmaf(t2.x, w[8],  a0); a1 = fmaf(t2.y, w[9],  a1);
    a2 = fmaf(t2.z, w[10], a2); a3 = fmaf(t2.w, w[11], a3);
    float part = (a0 + a1) + (a2 + a3);
    float tot = part + __shfl_xor(part, 32, 64);
    float tn = tot * sc;
    if (lane < KTAG) tau[lane] = tn;
    ref = tn;
  };
  if (n > 0) {
    LOAD(A, 0); LOAD(B, n > 1 ? 1 : 0); LOAD(Cb, n > 2 ? 2 : 0);
    int i = 0;
    while (i + 3 <= n) {
      STEP(A);  { int ii = i + 3; LOAD(A,  ii < n ? ii : n - 1); }
      STEP(B);  { int ii = i + 4; LOAD(B,  ii < n ? ii : n - 1); }
      STEP(Cb); { int ii = i + 5; LOAD(Cb, ii < n ? ii : n - 1); }
      i += 3;
    }
    if (i < n)     STEP(A);
    if (i + 1 < n) STEP(B);
  }
  return E;
}

__global__ __launch_bounds__(128) void crf_fb_kernel(
    const float* __restrict__ scores, const int* __restrict__ lengths,
    float* __restrict__ acc)
{
  __shared__ float sm[2][32];
  __shared__ int smE[2];
  const int b = blockIdx.x;
  const int tid = threadIdx.x;
  const int wid = tid >> 6;
  const int lane = tid & 63;
  const int h = lane >> 5;
  const int j = lane & 31;
  const int jj = j < KTAG ? j : KTAG - 1;
  const int len = lengths[b];
  const float* base = scores + (size_t)b * T_LEN * MAT;
  const int m = len >> 1;
  volatile float* tau = sm[wid];
  int E;
  if (wid == 0) {
    if (lane < KTAG) tau[lane] = fexp2(base[START_TAG * KTAG + lane] * LOG2E);
    E = run_chain<0>(base, len, m, tau, lane, h, jj);
  } else {
    if (lane < KTAG) tau[lane] = (lane == END_TAG) ? 1.0f : 0.0f;
    E = run_chain<1>(base, len, len - 1 - m, tau, lane, h, jj);
  }
  if (lane == 0) smE[wid] = E;
  __syncthreads();
  if (wid == 0) {
    float v = (lane < KTAG) ? sm[0][lane] * sm[1][lane] : 0.0f;
    #pragma unroll
    for (int off = 1; off < 32; off <<= 1) v += __shfl_xor(v, off, 64);
    if (lane == 0) {
      float res = ((float)(smE[0] + smE[1]) + flog2(v)) * LN2;
      atomicAdd(acc, res);
    }
  }
}

// gold = sum over (b, t<len) of scores[b,t].flat[targets[b,t]]; accumulated NEGATED.
__global__ __launch_bounds__(256) void gold_kernel(
    const float* __restrict__ scores, const int* __restrict__ targets,
    const int* __restrict__ lengths, float* __restrict__ acc)
{
  const int idx = blockIdx.x * blockDim.x + threadIdx.x;   // b*1024 + t
  const int b = idx >> 10;
  const int t = idx & (T_LEN - 1);
  float v = 0.f;
  if (t < lengths[b]) v = scores[(size_t)idx * MAT + targets[idx]];
  #pragma unroll
  for (int off = 1; off < 64; off <<= 1) v += __shfl_xor(v, off, 64);
  if ((threadIdx.x & 63) == 0) atomicAdd(acc, -v);
}

__global__ void finalize_kernel(const float* __restrict__ acc, float* __restrict__ out) {
  out[0] = acc[0] * (1.0f / (float)BATCH);
}

extern "C" void kernel_launch(void* const* d_in, const int* in_sizes, int n_in,
                              void* d_out, int out_size, void* d_ws, size_t ws_size,
                              hipStream_t stream) {
  const float* scores = (const float*)d_in[0];
  const int* targets  = (const int*)d_in[1];
  const int* lengths  = (const int*)d_in[2];
  float* out = (float*)d_out;
  float* acc = (float*)d_ws;

  const size_t pbytes = (size_t)BATCH * NCHUNK * MAT * sizeof(float);
  const size_t need = 256 + pbytes + (size_t)BATCH * NCHUNK * sizeof(int);

  hipMemsetAsync(acc, 0, sizeof(float), stream);
  gold_kernel<<<BATCH * T_LEN / 256, 256, 0, stream>>>(scores, targets, lengths, acc);

  if (ws_size >= need) {
    float* wsP = (float*)((char*)d_ws + 256);
    int* wsE = (int*)((char*)d_ws + 256 + pbytes);
    chunkprod_kernel<<<BATCH * NCHUNK / 4, 256, 0, stream>>>(scores, lengths, wsP, wsE);
    chainvec_kernel<<<BATCH, 64, 0, stream>>>(scores, wsP, wsE, lengths, acc);
  } else {
    crf_fb_kernel<<<BATCH, 128, 0, stream>>>(scores, lengths, acc);
  }
  finalize_kernel<<<1, 1, 0, stream>>>(acc, out);
}

// Round 5
// 93.250 us; speedup vs baseline: 3.8573x; 1.6558x over previous
//
#include <hip/hip_runtime.h>

static constexpr int T_LEN = 1024;
static constexpr int KTAG = 24;
static constexpr int MAT = 576;      // 24*24
static constexpr int START_TAG = 22;
static constexpr int END_TAG = 23;
static constexpr int BATCH = 128;
static constexpr int CHUNK = 32;     // time steps per chunk
static constexpr int NCHUNK = 32;

static constexpr float LOG2E = 1.4426950408889634f;
static constexpr float LN2   = 0.6931471805599453f;

typedef short  bf16x8 __attribute__((ext_vector_type(8)));
typedef float  f32x16 __attribute__((ext_vector_type(16)));

__device__ __forceinline__ float fexp2(float x) { return __builtin_amdgcn_exp2f(x); }
__device__ __forceinline__ float flog2(float x) { return __builtin_amdgcn_logf(x); }

// fp32 -> bf16 bits, round-to-nearest-even (branchless; inputs finite positive)
__device__ __forceinline__ unsigned int f2bf(float x) {
  unsigned int u = __float_as_uint(x);
  u += 0x7FFFu + ((u >> 16) & 1u);
  return u >> 16;
}

// ---------------------------------------------------------------------------
// Phase A (MFMA): per (batch,chunk) wave computes Q = W_{t0+n-1}^T ... W_{t0}^T
// (= P^T) via D = A·B pairs of mfma_f32_32x32x16_bf16, state Q as B-operand.
// k-slot permutation g(l): slot (hd,e) -> k = (e&3)+8*(e>>2)+4*hd (+16 mfma2)
// chosen so C/D regs pack DIRECTLY into next B frags (no cross-lane, no LDS).
// A slots with k>=24 (e>=4 in mfma2) are zero -> padding rows never pollute.
// Per-step 2^-d rescale folds into next A's exp2 arg. Gold partial fused.
// ---------------------------------------------------------------------------
__global__ __launch_bounds__(256) void chunkprod_kernel(
    const float* __restrict__ scores, const int* __restrict__ targets,
    const int* __restrict__ lengths,
    float* __restrict__ wsP, int* __restrict__ wsE, float* __restrict__ acc)
{
  const int widx = threadIdx.x >> 6;
  const int lane = threadIdx.x & 63;
  const int w = blockIdx.x * 4 + widx;
  const int b = w >> 5;
  const int c = w & (NCHUNK - 1);
  const int len = lengths[b];
  const int t0 = 1 + c * CHUNK;
  if (t0 >= len) return;                 // wave-uniform exit
  const int n = min(CHUNK, len - t0);
  const int hd = lane >> 5;
  const int m = lane & 31;
  const int mc = m < KTAG ? m : KTAG - 1;   // address clamp for padding rows
  const float* sb = scores + (size_t)b * T_LEN * MAT;

  // fused gold partial: t in [t0, t0+n)
  {
    float g = 0.f;
    if (lane < n) {
      int t = t0 + lane;
      g = sb[(size_t)t * MAT + targets[b * T_LEN + t]];
    }
    #pragma unroll
    for (int off = 1; off < 64; off <<= 1) g += __shfl_xor(g, off, 64);
    if (lane == 0) atomicAdd(acc, -g);
  }

  // A-load offsets (dwords) under the k-permutation
  int off1[8], off2[4];
  #pragma unroll
  for (int e = 0; e < 8; ++e) {
    int k = (e & 3) + 8 * (e >> 2) + 4 * hd;         // mfma1 global k
    off1[e] = k * KTAG + mc;
  }
  #pragma unroll
  for (int e = 0; e < 4; ++e) {
    int k = 16 + e + 4 * hd;                         // mfma2 global k (<24)
    off2[e] = k * KTAG + mc;
  }

  float bufA[12], bufB[12];
  auto LOADA = [&](float (&buf)[12], int step) {
    const float* pb = sb + (size_t)(t0 + step) * MAT;
    #pragma unroll
    for (int e = 0; e < 8; ++e) buf[e] = pb[off1[e]];
    #pragma unroll
    for (int e = 0; e < 4; ++e) buf[8 + e] = pb[off2[e]];
  };

  // B state: 8 packed uints (2 bf16 each). Init = identity under g().
  unsigned int p[8];
  #pragma unroll
  for (int r = 0; r < 8; ++r) {
    int rlo = ((2 * r) & 3) + 8 * ((2 * r) >> 2) + 4 * hd;  // rows are (rlo, rlo+1)
    unsigned int v = 0;
    if (m == rlo)     v |= 0x3F80u;
    if (m == rlo + 1) v |= (0x3F80u << 16);
    p[r] = v;
  }

  float negd = 0.f;
  int E = 0;
  f32x16 z;

  auto STEPM = [&](const float (&buf)[12]) -> f32x16 {
    float av[12];
    #pragma unroll
    for (int i = 0; i < 12; ++i) av[i] = fexp2(fmaf(buf[i], LOG2E, negd));
    bf16x8 a1, a2;
    #pragma unroll
    for (int e = 0; e < 8; ++e) a1[e] = (short)f2bf(av[e]);
    #pragma unroll
    for (int e = 0; e < 4; ++e) a2[e] = (short)f2bf(av[8 + e]);
    #pragma unroll
    for (int e = 4; e < 8; ++e) a2[e] = 0;                   // k>=24 padding
    union { unsigned int u[4]; bf16x8 v; } B1, B2;
    B1.u[0] = p[0]; B1.u[1] = p[1]; B1.u[2] = p[2]; B1.u[3] = p[3];
    B2.u[0] = p[4]; B2.u[1] = p[5]; B2.u[2] = p[6]; B2.u[3] = p[7];
    f32x16 d = {};
    d = __builtin_amdgcn_mfma_f32_32x32x16_bf16(a1, B1.v, d, 0, 0, 0);
    d = __builtin_amdgcn_mfma_f32_32x32x16_bf16(a2, B2.v, d, 0, 0, 0);
    return d;
  };

  auto CONV = [&](const f32x16& d) {      // D -> next B, extract rescale
    int rb = __builtin_amdgcn_readfirstlane(__float_as_int(d[0]));
    int dd = ((rb >> 23) & 255) - 127;
    E += dd;
    negd = (float)(-dd);
    #pragma unroll
    for (int r = 0; r < 8; ++r)
      p[r] = (f2bf(d[2 * r + 1]) << 16) | f2bf(d[2 * r]);
  };

  LOADA(bufA, 0);
  LOADA(bufB, n > 1 ? 1 : 0);
  int s = 0;
  for (;;) {
    z = STEPM(bufA);                       // step s
    if (s + 1 >= n) break;
    CONV(z);
    { int t = s + 2; LOADA(bufA, t < n ? t : n - 1); }
    z = STEPM(bufB);                       // step s+1
    if (s + 2 >= n) break;
    CONV(z);
    { int t = s + 3; LOADA(bufB, t < n ? t : n - 1); }
    s += 2;
  }

  // store P = Q^T row m (cols from C/D reg map); regs 12..15 are padding rows
  if (m < KTAG) {
    float* dst = wsP + (size_t)(b * NCHUNK + c) * MAT + m * KTAG;
    float4 v0 = make_float4(z[0], z[1], z[2],  z[3]);
    float4 v1 = make_float4(z[4], z[5], z[6],  z[7]);
    float4 v2 = make_float4(z[8], z[9], z[10], z[11]);
    *(float4*)(dst + 4 * hd)      = v0;    // q-rows 0-3 / 4-7
    *(float4*)(dst + 8 + 4 * hd)  = v1;    // 8-11 / 12-15
    *(float4*)(dst + 16 + 4 * hd) = v2;    // 16-19 / 20-23
  }
  if (lane == 0) wsE[b * NCHUNK + c] = E;
}

// ---------------------------------------------------------------------------
// Phase B: one wave per batch folds chunk matrices into v0 (<=32 matvecs).
// Also adds the t=0 gold term.
// ---------------------------------------------------------------------------
__global__ __launch_bounds__(64) void chainvec_kernel(
    const float* __restrict__ scores, const int* __restrict__ targets,
    const float* __restrict__ wsP, const int* __restrict__ wsE,
    const int* __restrict__ lengths, float* __restrict__ acc)
{
  __shared__ float tau_s[32];
  volatile float* tau = tau_s;
  const int b = blockIdx.x;
  const int lane = threadIdx.x;
  const int h = lane >> 5;
  const int j = lane & 31;
  const int jj = j < KTAG ? j : KTAG - 1;
  const int len = lengths[b];
  const int nc = (len + 30) >> 5;        // ceil((len-1)/32)

  if (lane < KTAG)
    tau[lane] = fexp2(scores[(size_t)b * T_LEN * MAT + START_TAG * KTAG + lane] * LOG2E);

  int E = 0;
  float wa[12], wb[12];

  auto LOADV = [&](float (&buf)[12], int c) {
    const float* p = wsP + (size_t)(b * NCHUNK + c) * MAT + (h * 12) * KTAG + jj;
    #pragma unroll
    for (int k = 0; k < 12; ++k) buf[k] = p[k * KTAG];
  };
  auto STEPV = [&](const float (&buf)[12], int c) {
    int ec = wsE[b * NCHUNK + c];
    const float4* tp = (const float4*)((const float*)&tau_s[h * 12]);
    float4 t0 = tp[0], t1 = tp[1], t2 = tp[2];
    float a0 = t0.x * buf[0], a1 = t0.y * buf[1], a2 = t0.z * buf[2], a3 = t0.w * buf[3];
    a0 = fmaf(t1.x, buf[4],  a0); a1 = fmaf(t1.y, buf[5],  a1);
    a2 = fmaf(t1.z, buf[6],  a2); a3 = fmaf(t1.w, buf[7],  a3);
    a0 = fmaf(t2.x, buf[8],  a0); a1 = fmaf(t2.y, buf[9],  a1);
    a2 = fmaf(t2.z, buf[10], a2); a3 = fmaf(t2.w, buf[11], a3);
    float part = (a0 + a1) + (a2 + a3);
    float tot = part + __shfl_xor(part, 32, 64);
    int rb = __builtin_amdgcn_readfirstlane(__float_as_int(tot));
    int d = ((rb >> 23) & 255) - 127;
    E += d + ec;
    float sc = __int_as_float((127 - d) << 23);
    if (lane < KTAG) tau[lane] = tot * sc;
  };

  if (nc > 0) {
    LOADV(wa, 0);
    LOADV(wb, nc > 1 ? 1 : 0);
    int c = 0;
    while (c + 1 < nc) {
      STEPV(wa, c);     { int t = c + 2; LOADV(wa, t < nc ? t : nc - 1); }
      STEPV(wb, c + 1); { int t = c + 3; LOADV(wb, t < nc ? t : nc - 1); }
      c += 2;
    }
    if (c < nc) STEPV(wa, c);
  }

  if (lane == 0) {
    // t=0 gold term (t=0 < len always)
    float g0 = scores[(size_t)b * T_LEN * MAT + targets[b * T_LEN]];
    float res = ((float)E + flog2(tau[END_TAG])) * LN2;
    atomicAdd(acc, res - g0);
  }
}

// ---------------------------------------------------------------------------
// Fallback path (R2-verified sequential FB) — only if ws_size too small.
// ---------------------------------------------------------------------------
template<int DIR>
__device__ __forceinline__ int run_chain(const float* __restrict__ base, int len, int n,
                                         volatile float* __restrict__ tau,
                                         int lane, int h, int jj)
{
  int E = 0;
  float ref = 1.0f;
  float A[12], B[12], Cb[12];
  auto LOAD = [&](float (&buf)[12], int i) {
    if (DIR == 0) {
      const float* p = base + (size_t)(1 + i) * MAT + h * 12 * KTAG + jj;
      #pragma unroll
      for (int k = 0; k < 12; ++k) buf[k] = p[k * KTAG];
    } else {
      const float4* p = (const float4*)(base + (size_t)(len - 1 - i) * MAT + jj * KTAG + h * 12);
      float4 x = p[0], y = p[1], z = p[2];
      buf[0]=x.x; buf[1]=x.y; buf[2]=x.z; buf[3]=x.w;
      buf[4]=y.x; buf[5]=y.y; buf[6]=y.z; buf[7]=y.w;
      buf[8]=z.x; buf[9]=z.y; buf[10]=z.z; buf[11]=z.w;
    }
  };
  auto STEP = [&](const float (&buf)[12]) {
    int rb = __builtin_amdgcn_readfirstlane(__float_as_int(ref));
    int d = ((rb >> 23) & 255) - 127;
    float sc = __int_as_float((127 - d) << 23);
    E += d;
    float w[12];
    #pragma unroll
    for (int k = 0; k < 12; ++k) w[k] = fexp2(buf[k] * LOG2E);
    const float4* tp = (const float4*)((const float*)&tau[h * 12]);
    float4 t0 = tp[0], t1 = tp[1], t2 = tp[2];
    float a0 = t0.x*w[0], a1 = t0.y*w[1], a2 = t0.z*w[2], a3 = t0.w*w[3];
    a0 = fmaf(t1.x, w[4],  a0); a1 = fmaf(t1.y, w[5],  a1);
    a2 = fmaf(t1.z, w[6],  a2); a3 = fmaf(t1.w, w[7],  a3);
    a0 = fmaf(t2.x, w[8],  a0); a1 = fmaf(t2.y, w[9],  a1);
    a2 = fmaf(t2.z, w[10], a2); a3 = fmaf(t2.w, w[11], a3);
    float part = (a0 + a1) + (a2 + a3);
    float tot = part + __shfl_xor(part, 32, 64);
    float tn = tot * sc;
    if (lane < KTAG) tau[lane] = tn;
    ref = tn;
  };
  if (n > 0) {
    LOAD(A, 0); LOAD(B, n > 1 ? 1 : 0); LOAD(Cb, n > 2 ? 2 : 0);
    int i = 0;
    while (i + 3 <= n) {
      STEP(A);  { int ii = i + 3; LOAD(A,  ii < n ? ii : n - 1); }
      STEP(B);  { int ii = i + 4; LOAD(B,  ii < n ? ii : n - 1); }
      STEP(Cb); { int ii = i + 5; LOAD(Cb, ii < n ? ii : n - 1); }
      i += 3;
    }
    if (i < n)     STEP(A);
    if (i + 1 < n) STEP(B);
  }
  return E;
}

__global__ __launch_bounds__(128) void crf_fb_kernel(
    const float* __restrict__ scores, const int* __restrict__ lengths,
    float* __restrict__ acc)
{
  __shared__ float sm[2][32];
  __shared__ int smE[2];
  const int b = blockIdx.x;
  const int tid = threadIdx.x;
  const int wid = tid >> 6;
  const int lane = tid & 63;
  const int h = lane >> 5;
  const int j = lane & 31;
  const int jj = j < KTAG ? j : KTAG - 1;
  const int len = lengths[b];
  const float* base = scores + (size_t)b * T_LEN * MAT;
  const int m = len >> 1;
  volatile float* tau = sm[wid];
  int E;
  if (wid == 0) {
    if (lane < KTAG) tau[lane] = fexp2(base[START_TAG * KTAG + lane] * LOG2E);
    E = run_chain<0>(base, len, m, tau, lane, h, jj);
  } else {
    if (lane < KTAG) tau[lane] = (lane == END_TAG) ? 1.0f : 0.0f;
    E = run_chain<1>(base, len, len - 1 - m, tau, lane, h, jj);
  }
  if (lane == 0) smE[wid] = E;
  __syncthreads();
  if (wid == 0) {
    float v = (lane < KTAG) ? sm[0][lane] * sm[1][lane] : 0.0f;
    #pragma unroll
    for (int off = 1; off < 32; off <<= 1) v += __shfl_xor(v, off, 64);
    if (lane == 0) {
      float res = ((float)(smE[0] + smE[1]) + flog2(v)) * LN2;
      atomicAdd(acc, res);
    }
  }
}

__global__ __launch_bounds__(256) void gold_kernel(
    const float* __restrict__ scores, const int* __restrict__ targets,
    const int* __restrict__ lengths, float* __restrict__ acc)
{
  const int idx = blockIdx.x * blockDim.x + threadIdx.x;
  const int b = idx >> 10;
  const int t = idx & (T_LEN - 1);
  float v = 0.f;
  if (t < lengths[b]) v = scores[(size_t)idx * MAT + targets[idx]];
  #pragma unroll
  for (int off = 1; off < 64; off <<= 1) v += __shfl_xor(v, off, 64);
  if ((threadIdx.x & 63) == 0) atomicAdd(acc, -v);
}

__global__ void finalize_kernel(const float* __restrict__ acc, float* __restrict__ out) {
  out[0] = acc[0] * (1.0f / (float)BATCH);
}

extern "C" void kernel_launch(void* const* d_in, const int* in_sizes, int n_in,
                              void* d_out, int out_size, void* d_ws, size_t ws_size,
                              hipStream_t stream) {
  const float* scores = (const float*)d_in[0];
  const int* targets  = (const int*)d_in[1];
  const int* lengths  = (const int*)d_in[2];
  float* out = (float*)d_out;
  float* acc = (float*)d_ws;

  const size_t pbytes = (size_t)BATCH * NCHUNK * MAT * sizeof(float);
  const size_t need = 256 + pbytes + (size_t)BATCH * NCHUNK * sizeof(int);

  hipMemsetAsync(acc, 0, sizeof(float), stream);

  if (ws_size >= need) {
    float* wsP = (float*)((char*)d_ws + 256);
    int* wsE = (int*)((char*)d_ws + 256 + pbytes);
    chunkprod_kernel<<<BATCH * NCHUNK / 4, 256, 0, stream>>>(scores, targets, lengths,
                                                             wsP, wsE, acc);
    chainvec_kernel<<<BATCH, 64, 0, stream>>>(scores, targets, wsP, wsE, lengths, acc);
  } else {
    gold_kernel<<<BATCH * T_LEN / 256, 256, 0, stream>>>(scores, targets, lengths, acc);
    crf_fb_kernel<<<BATCH, 128, 0, stream>>>(scores, lengths, acc);
  }
  finalize_kernel<<<1, 1, 0, stream>>>(acc, out);
}

// Round 8
// 91.588 us; speedup vs baseline: 3.9273x; 1.0181x over previous
//
#include <hip/hip_runtime.h>

static constexpr int T_LEN = 1024;
static constexpr int KTAG = 24;
static constexpr int MAT = 576;      // 24*24
static constexpr int START_TAG = 22;
static constexpr int END_TAG = 23;
static constexpr int BATCH = 128;
static constexpr int CHUNK = 32;     // time steps per chunk
static constexpr int NCHUNK = 32;

static constexpr float LOG2E = 1.4426950408889634f;
static constexpr float LN2   = 0.6931471805599453f;

typedef short  bf16x8 __attribute__((ext_vector_type(8)));
typedef float  f32x16 __attribute__((ext_vector_type(16)));

__device__ __forceinline__ float fexp2(float x) { return __builtin_amdgcn_exp2f(x); }
__device__ __forceinline__ float flog2(float x) { return __builtin_amdgcn_logf(x); }

// fp32 -> bf16 bits, round-to-nearest-even (branchless; inputs finite positive)
__device__ __forceinline__ unsigned int f2bf(float x) {
  unsigned int u = __float_as_uint(x);
  u += 0x7FFFu + ((u >> 16) & 1u);
  return u >> 16;
}

// ---------------------------------------------------------------------------
// Phase A (MFMA): per (batch,chunk) wave computes Q = W_{t0+n-1}^T ... W_{t0}^T
// (= P^T) via D = A·B pairs of mfma_f32_32x32x16_bf16, state Q as B-operand.
// k-slot permutation g(l): slot (hd,e) -> k = (e&3)+8*(e>>2)+4*hd (+16 mfma2)
// chosen so C/D regs pack DIRECTLY into next B frags (no cross-lane, no LDS).
// A slots with k>=24 (e>=4 in mfma2) are zero -> padding rows never pollute.
// Per-step 2^-d rescale folds into next A's exp2 arg (VERIFIED R5 math).
// ONLY change vs the R5-passing kernel: prefetch depth 2 -> 4 (MLP bisect).
// ---------------------------------------------------------------------------
__global__ __launch_bounds__(256) void chunkprod_kernel(
    const float* __restrict__ scores, const int* __restrict__ targets,
    const int* __restrict__ lengths,
    float* __restrict__ wsP, int* __restrict__ wsE, float* __restrict__ acc)
{
  const int widx = threadIdx.x >> 6;
  const int lane = threadIdx.x & 63;
  const int w = blockIdx.x * 4 + widx;
  const int b = w >> 5;
  const int c = w & (NCHUNK - 1);
  const int len = lengths[b];
  const int t0 = 1 + c * CHUNK;
  if (t0 >= len) return;                 // wave-uniform exit
  const int n = min(CHUNK, len - t0);
  const int hd = lane >> 5;
  const int m = lane & 31;
  const int mc = m < KTAG ? m : KTAG - 1;   // address clamp for padding rows
  const float* sb = scores + (size_t)b * T_LEN * MAT;

  // fused gold partial: t in [t0, t0+n)
  {
    float g = 0.f;
    if (lane < n) {
      int t = t0 + lane;
      g = sb[(size_t)t * MAT + targets[b * T_LEN + t]];
    }
    #pragma unroll
    for (int off = 1; off < 64; off <<= 1) g += __shfl_xor(g, off, 64);
    if (lane == 0) atomicAdd(acc, -g);
  }

  // A-load offsets (dwords) under the k-permutation
  int off1[8], off2[4];
  #pragma unroll
  for (int e = 0; e < 8; ++e) {
    int k = (e & 3) + 8 * (e >> 2) + 4 * hd;         // mfma1 global k
    off1[e] = k * KTAG + mc;
  }
  #pragma unroll
  for (int e = 0; e < 4; ++e) {
    int k = 16 + e + 4 * hd;                         // mfma2 global k (<24)
    off2[e] = k * KTAG + mc;
  }

  float b0[12], b1[12], b2[12], b3[12];
  auto LOADA = [&](float (&buf)[12], int step) {
    const float* pb = sb + (size_t)(t0 + step) * MAT;
    #pragma unroll
    for (int e = 0; e < 8; ++e) buf[e] = pb[off1[e]];
    #pragma unroll
    for (int e = 0; e < 4; ++e) buf[8 + e] = pb[off2[e]];
  };

  // B state: 8 packed uints (2 bf16 each). Init = identity under g().
  unsigned int p[8];
  #pragma unroll
  for (int r = 0; r < 8; ++r) {
    int rlo = ((2 * r) & 3) + 8 * ((2 * r) >> 2) + 4 * hd;  // rows (rlo, rlo+1)
    unsigned int v = 0;
    if (m == rlo)     v |= 0x3F80u;
    if (m == rlo + 1) v |= (0x3F80u << 16);
    p[r] = v;
  }

  float negd = 0.f;
  int E = 0;

  auto STEPM = [&](const float (&buf)[12]) -> f32x16 {
    float av[12];
    #pragma unroll
    for (int i = 0; i < 12; ++i) av[i] = fexp2(fmaf(buf[i], LOG2E, negd));
    bf16x8 a1, a2;
    #pragma unroll
    for (int e = 0; e < 8; ++e) a1[e] = (short)f2bf(av[e]);
    #pragma unroll
    for (int e = 0; e < 4; ++e) a2[e] = (short)f2bf(av[8 + e]);
    #pragma unroll
    for (int e = 4; e < 8; ++e) a2[e] = 0;                   // k>=24 padding
    union { unsigned int u[4]; bf16x8 v; } B1, B2;
    B1.u[0] = p[0]; B1.u[1] = p[1]; B1.u[2] = p[2]; B1.u[3] = p[3];
    B2.u[0] = p[4]; B2.u[1] = p[5]; B2.u[2] = p[6]; B2.u[3] = p[7];
    f32x16 d = {};
    d = __builtin_amdgcn_mfma_f32_32x32x16_bf16(a1, B1.v, d, 0, 0, 0);
    d = __builtin_amdgcn_mfma_f32_32x32x16_bf16(a2, B2.v, d, 0, 0, 0);
    return d;
  };

  auto CONV = [&](const f32x16& d) {      // D -> next B, extract rescale
    int rb = __builtin_amdgcn_readfirstlane(__float_as_int(d[0]));
    int dd = ((rb >> 23) & 255) - 127;
    E += dd;
    negd = (float)(-dd);
    #pragma unroll
    for (int r = 0; r < 8; ++r)
      p[r] = (f2bf(d[2 * r + 1]) << 16) | f2bf(d[2 * r]);
  };

  LOADA(b0, 0);
  LOADA(b1, n > 1 ? 1 : 0);
  LOADA(b2, n > 2 ? 2 : 0);
  LOADA(b3, n > 3 ? 3 : 0);
  f32x16 z;
  int s = 0;
  for (;;) {
    z = STEPM(b0);                                   // step s
    if (s + 1 >= n) break;
    CONV(z); { int t = s + 4; LOADA(b0, t < n ? t : n - 1); }
    z = STEPM(b1);                                   // step s+1
    if (s + 2 >= n) break;
    CONV(z); { int t = s + 5; LOADA(b1, t < n ? t : n - 1); }
    z = STEPM(b2);                                   // step s+2
    if (s + 3 >= n) break;
    CONV(z); { int t = s + 6; LOADA(b2, t < n ? t : n - 1); }
    z = STEPM(b3);                                   // step s+3
    if (s + 4 >= n) break;
    CONV(z); { int t = s + 7; LOADA(b3, t < n ? t : n - 1); }
    s += 4;
  }

  // store P = Q^T row m (cols from C/D reg map); regs 12..15 are padding rows
  if (m < KTAG) {
    float* dst = wsP + (size_t)(b * NCHUNK + c) * MAT + m * KTAG;
    float4 v0 = make_float4(z[0], z[1], z[2],  z[3]);
    float4 v1 = make_float4(z[4], z[5], z[6],  z[7]);
    float4 v2 = make_float4(z[8], z[9], z[10], z[11]);
    *(float4*)(dst + 4 * hd)      = v0;    // q-rows 0-3 / 4-7
    *(float4*)(dst + 8 + 4 * hd)  = v1;    // 8-11 / 12-15
    *(float4*)(dst + 16 + 4 * hd) = v2;    // 16-19 / 20-23
  }
  if (lane == 0) wsE[b * NCHUNK + c] = E;
}

// ---------------------------------------------------------------------------
// Phase B: one wave per batch folds chunk matrices into v0 (<=32 matvecs);
// adds the t=0 gold term.
// ---------------------------------------------------------------------------
__global__ __launch_bounds__(64) void chainvec_kernel(
    const float* __restrict__ scores, const int* __restrict__ targets,
    const float* __restrict__ wsP, const int* __restrict__ wsE,
    const int* __restrict__ lengths, float* __restrict__ acc)
{
  __shared__ float tau_s[32];
  volatile float* tau = tau_s;
  const int b = blockIdx.x;
  const int lane = threadIdx.x;
  const int h = lane >> 5;
  const int j = lane & 31;
  const int jj = j < KTAG ? j : KTAG - 1;
  const int len = lengths[b];
  const int nc = (len + 30) >> 5;        // ceil((len-1)/32)

  if (lane < KTAG)
    tau[lane] = fexp2(scores[(size_t)b * T_LEN * MAT + START_TAG * KTAG + lane] * LOG2E);

  int E = 0;
  float wa[12], wb[12];

  auto LOADV = [&](float (&buf)[12], int c) {
    const float* p = wsP + (size_t)(b * NCHUNK + c) * MAT + (h * 12) * KTAG + jj;
    #pragma unroll
    for (int k = 0; k < 12; ++k) buf[k] = p[k * KTAG];
  };
  auto STEPV = [&](const float (&buf)[12], int c) {
    int ec = wsE[b * NCHUNK + c];
    const float4* tp = (const float4*)((const float*)&tau_s[h * 12]);
    float4 t0 = tp[0], t1 = tp[1], t2 = tp[2];
    float a0 = t0.x * buf[0], a1 = t0.y * buf[1], a2 = t0.z * buf[2], a3 = t0.w * buf[3];
    a0 = fmaf(t1.x, buf[4],  a0); a1 = fmaf(t1.y, buf[5],  a1);
    a2 = fmaf(t1.z, buf[6],  a2); a3 = fmaf(t1.w, buf[7],  a3);
    a0 = fmaf(t2.x, buf[8],  a0); a1 = fmaf(t2.y, buf[9],  a1);
    a2 = fmaf(t2.z, buf[10], a2); a3 = fmaf(t2.w, buf[11], a3);
    float part = (a0 + a1) + (a2 + a3);
    float tot = part + __shfl_xor(part, 32, 64);
    int rb = __builtin_amdgcn_readfirstlane(__float_as_int(tot));
    int d = ((rb >> 23) & 255) - 127;
    E += d + ec;
    float sc = __int_as_float((127 - d) << 23);
    if (lane < KTAG) tau[lane] = tot * sc;
  };

  if (nc > 0) {
    LOADV(wa, 0);
    LOADV(wb, nc > 1 ? 1 : 0);
    int c = 0;
    while (c + 1 < nc) {
      STEPV(wa, c);     { int t = c + 2; LOADV(wa, t < nc ? t : nc - 1); }
      STEPV(wb, c + 1); { int t = c + 3; LOADV(wb, t < nc ? t : nc - 1); }
      c += 2;
    }
    if (c < nc) STEPV(wa, c);
  }

  if (lane == 0) {
    float g0 = scores[(size_t)b * T_LEN * MAT + targets[b * T_LEN]];  // t=0 gold
    float res = ((float)E + flog2(tau[END_TAG])) * LN2;
    atomicAdd(acc, res - g0);
  }
}

// ---------------------------------------------------------------------------
// Fallback path (R2-verified sequential FB) — only if ws_size too small.
// ---------------------------------------------------------------------------
template<int DIR>
__device__ __forceinline__ int run_chain(const float* __restrict__ base, int len, int n,
                                         volatile float* __restrict__ tau,
                                         int lane, int h, int jj)
{
  int E = 0;
  float ref = 1.0f;
  float A[12], B[12], Cb[12];
  auto LOAD = [&](float (&buf)[12], int i) {
    if (DIR == 0) {
      const float* p = base + (size_t)(1 + i) * MAT + h * 12 * KTAG + jj;
      #pragma unroll
      for (int k = 0; k < 12; ++k) buf[k] = p[k * KTAG];
    } else {
      const float4* p = (const float4*)(base + (size_t)(len - 1 - i) * MAT + jj * KTAG + h * 12);
      float4 x = p[0], y = p[1], z = p[2];
      buf[0]=x.x; buf[1]=x.y; buf[2]=x.z; buf[3]=x.w;
      buf[4]=y.x; buf[5]=y.y; buf[6]=y.z; buf[7]=y.w;
      buf[8]=z.x; buf[9]=z.y; buf[10]=z.z; buf[11]=z.w;
    }
  };
  auto STEP = [&](const float (&buf)[12]) {
    int rb = __builtin_amdgcn_readfirstlane(__float_as_int(ref));
    int d = ((rb >> 23) & 255) - 127;
    float sc = __int_as_float((127 - d) << 23);
    E += d;
    float w[12];
    #pragma unroll
    for (int k = 0; k < 12; ++k) w[k] = fexp2(buf[k] * LOG2E);
    const float4* tp = (const float4*)((const float*)&tau[h * 12]);
    float4 t0 = tp[0], t1 = tp[1], t2 = tp[2];
    float a0 = t0.x*w[0], a1 = t0.y*w[1], a2 = t0.z*w[2], a3 = t0.w*w[3];
    a0 = fmaf(t1.x, w[4],  a0); a1 = fmaf(t1.y, w[5],  a1);
    a2 = fmaf(t1.z, w[6],  a2); a3 = fmaf(t1.w, w[7],  a3);
    a0 = fmaf(t2.x, w[8],  a0); a1 = fmaf(t2.y, w[9],  a1);
    a2 = fmaf(t2.z, w[10], a2); a3 = fmaf(t2.w, w[11], a3);
    float part = (a0 + a1) + (a2 + a3);
    float tot = part + __shfl_xor(part, 32, 64);
    float tn = tot * sc;
    if (lane < KTAG) tau[lane] = tn;
    ref = tn;
  };
  if (n > 0) {
    LOAD(A, 0); LOAD(B, n > 1 ? 1 : 0); LOAD(Cb, n > 2 ? 2 : 0);
    int i = 0;
    while (i + 3 <= n) {
      STEP(A);  { int ii = i + 3; LOAD(A,  ii < n ? ii : n - 1); }
      STEP(B);  { int ii = i + 4; LOAD(B,  ii < n ? ii : n - 1); }
      STEP(Cb); { int ii = i + 5; LOAD(Cb, ii < n ? ii : n - 1); }
      i += 3;
    }
    if (i < n)     STEP(A);
    if (i + 1 < n) STEP(B);
  }
  return E;
}

__global__ __launch_bounds__(128) void crf_fb_kernel(
    const float* __restrict__ scores, const int* __restrict__ lengths,
    float* __restrict__ acc)
{
  __shared__ float sm[2][32];
  __shared__ int smE[2];
  const int b = blockIdx.x;
  const int tid = threadIdx.x;
  const int wid = tid >> 6;
  const int lane = tid & 63;
  const int h = lane >> 5;
  const int j = lane & 31;
  const int jj = j < KTAG ? j : KTAG - 1;
  const int len = lengths[b];
  const float* base = scores + (size_t)b * T_LEN * MAT;
  const int m = len >> 1;
  volatile float* tau = sm[wid];
  int E;
  if (wid == 0) {
    if (lane < KTAG) tau[lane] = fexp2(base[START_TAG * KTAG + lane] * LOG2E);
    E = run_chain<0>(base, len, m, tau, lane, h, jj);
  } else {
    if (lane < KTAG) tau[lane] = (lane == END_TAG) ? 1.0f : 0.0f;
    E = run_chain<1>(base, len, len - 1 - m, tau, lane, h, jj);
  }
  if (lane == 0) smE[wid] = E;
  __syncthreads();
  if (wid == 0) {
    float v = (lane < KTAG) ? sm[0][lane] * sm[1][lane] : 0.0f;
    #pragma unroll
    for (int off = 1; off < 32; off <<= 1) v += __shfl_xor(v, off, 64);
    if (lane == 0) {
      float res = ((float)(smE[0] + smE[1]) + flog2(v)) * LN2;
      atomicAdd(acc, res);
    }
  }
}

__global__ __launch_bounds__(256) void gold_kernel(
    const float* __restrict__ scores, const int* __restrict__ targets,
    const int* __restrict__ lengths, float* __restrict__ acc)
{
  const int idx = blockIdx.x * blockDim.x + threadIdx.x;
  const int b = idx >> 10;
  const int t = idx & (T_LEN - 1);
  float v = 0.f;
  if (t < lengths[b]) v = scores[(size_t)idx * MAT + targets[idx]];
  #pragma unroll
  for (int off = 1; off < 64; off <<= 1) v += __shfl_xor(v, off, 64);
  if ((threadIdx.x & 63) == 0) atomicAdd(acc, -v);
}

__global__ void finalize_kernel(const float* __restrict__ acc, float* __restrict__ out) {
  out[0] = acc[0] * (1.0f / (float)BATCH);
}

extern "C" void kernel_launch(void* const* d_in, const int* in_sizes, int n_in,
                              void* d_out, int out_size, void* d_ws, size_t ws_size,
                              hipStream_t stream) {
  const float* scores = (const float*)d_in[0];
  const int* targets  = (const int*)d_in[1];
  const int* lengths  = (const int*)d_in[2];
  float* out = (float*)d_out;
  float* acc = (float*)d_ws;

  const size_t pbytes = (size_t)BATCH * NCHUNK * MAT * sizeof(float);
  const size_t need = 256 + pbytes + (size_t)BATCH * NCHUNK * sizeof(int);

  hipMemsetAsync(acc, 0, sizeof(float), stream);

  if (ws_size >= need) {
    float* wsP = (float*)((char*)d_ws + 256);
    int* wsE = (int*)((char*)d_ws + 256 + pbytes);
    chunkprod_kernel<<<BATCH * NCHUNK / 4, 256, 0, stream>>>(scores, targets, lengths,
                                                             wsP, wsE, acc);
    chainvec_kernel<<<BATCH, 64, 0, stream>>>(scores, targets, wsP, wsE, lengths, acc);
  } else {
    gold_kernel<<<BATCH * T_LEN / 256, 256, 0, stream>>>(scores, targets, lengths, acc);
    crf_fb_kernel<<<BATCH, 128, 0, stream>>>(scores, lengths, acc);
  }
  finalize_kernel<<<1, 1, 0, stream>>>(acc, out);
}

// Round 9
// 68.791 us; speedup vs baseline: 5.2288x; 1.3314x over previous
//
#include <hip/hip_runtime.h>

static constexpr int T_LEN = 1024;
static constexpr int KTAG = 24;
static constexpr int MAT = 576;      // 24*24
static constexpr int START_TAG = 22;
static constexpr int END_TAG = 23;
static constexpr int BATCH = 128;
static constexpr int CHUNK = 32;     // time steps per chunk
static constexpr int NCHUNK = 32;

static constexpr float LOG2E = 1.4426950408889634f;
static constexpr float LN2   = 0.6931471805599453f;

typedef short  bf16x8 __attribute__((ext_vector_type(8)));
typedef float  f32x16 __attribute__((ext_vector_type(16)));

__device__ __forceinline__ float fexp2(float x) { return __builtin_amdgcn_exp2f(x); }
__device__ __forceinline__ float flog2(float x) { return __builtin_amdgcn_logf(x); }

// fp32 -> bf16 bits, round-to-nearest-even (branchless; inputs finite positive)
__device__ __forceinline__ unsigned int f2bf(float x) {
  unsigned int u = __float_as_uint(x);
  u += 0x7FFFu + ((u >> 16) & 1u);
  return u >> 16;
}

// ---------------------------------------------------------------------------
// Phase A (MFMA): per-(batch,chunk) wave computes Q = W_{t0+n-1}^T ... W_{t0}^T
// via pairs of mfma_f32_32x32x16_bf16, state Q as B-operand (R5/R7-verified
// k-slot permutation: slot(hd,e) -> k=(e&3)+8*(e>>2)+4*hd, +16 for mfma2).
// CHANGES vs R7 (verified): (1) wave->(b,c) via bitrev7 so each block's 4
// waves span 4 length-quartiles (kills the 2x static imbalance);
// (2) rescale moved from next-A exp2 arg to pack-time exact 2^-dd multiply
// (f2bf packs, NOT cvtpk asm) -> A-prep off the serial chain;
// (3) gold partial -> wsG slot (no atomic, no memset needed).
// ---------------------------------------------------------------------------
__global__ __launch_bounds__(256) void chunkprod_kernel(
    const float* __restrict__ scores, const int* __restrict__ targets,
    const int* __restrict__ lengths,
    float* __restrict__ wsP, int* __restrict__ wsE, float* __restrict__ wsG)
{
  const int widx = threadIdx.x >> 6;
  const int lane = threadIdx.x & 63;
  const int g = blockIdx.x * 4 + widx;
  const int b = (int)(__brev((unsigned)(g & 127)) >> 25);   // bitrev7: bijection
  const int c = g >> 7;
  const int len = lengths[b];
  const int t0 = 1 + c * CHUNK;
  if (t0 >= len) return;                 // wave-uniform exit; slot never read
  const int n = min(CHUNK, len - t0);
  const int hd = lane >> 5;
  const int m = lane & 31;
  const int mc = m < KTAG ? m : KTAG - 1;   // address clamp for padding rows
  const float* sb = scores + (size_t)b * T_LEN * MAT;

  // fused gold partial: t in [t0, t0+n) -> wsG slot (no atomic)
  {
    float gs = 0.f;
    if (lane < n) {
      int t = t0 + lane;
      gs = sb[(size_t)t * MAT + targets[b * T_LEN + t]];
    }
    #pragma unroll
    for (int off = 1; off < 64; off <<= 1) gs += __shfl_xor(gs, off, 64);
    if (lane == 0) wsG[b * NCHUNK + c] = gs;
  }

  // A-load offsets (dwords) under the k-permutation
  int off1[8], off2[4];
  #pragma unroll
  for (int e = 0; e < 8; ++e) {
    int k = (e & 3) + 8 * (e >> 2) + 4 * hd;         // mfma1 global k
    off1[e] = k * KTAG + mc;
  }
  #pragma unroll
  for (int e = 0; e < 4; ++e) {
    int k = 16 + e + 4 * hd;                         // mfma2 global k (<24)
    off2[e] = k * KTAG + mc;
  }

  float b0[12], b1[12], b2[12], b3[12];
  auto LOADA = [&](float (&buf)[12], int step) {
    const float* pb = sb + (size_t)(t0 + step) * MAT;
    #pragma unroll
    for (int e = 0; e < 8; ++e) buf[e] = pb[off1[e]];
    #pragma unroll
    for (int e = 0; e < 4; ++e) buf[8 + e] = pb[off2[e]];
  };

  // B state: 8 packed uints (2 bf16 each). Init = identity under g().
  unsigned int p[8];
  #pragma unroll
  for (int r = 0; r < 8; ++r) {
    int rlo = ((2 * r) & 3) + 8 * ((2 * r) >> 2) + 4 * hd;  // rows (rlo, rlo+1)
    unsigned int v = 0;
    if (m == rlo)     v |= 0x3F80u;
    if (m == rlo + 1) v |= (0x3F80u << 16);
    p[r] = v;
  }

  int E = 0;

  auto STEPM = [&](const float (&buf)[12]) -> f32x16 {
    float av[12];
    #pragma unroll
    for (int i = 0; i < 12; ++i) av[i] = fexp2(buf[i] * LOG2E);  // loads-only dep
    bf16x8 a1, a2;
    #pragma unroll
    for (int e = 0; e < 8; ++e) a1[e] = (short)f2bf(av[e]);
    #pragma unroll
    for (int e = 0; e < 4; ++e) a2[e] = (short)f2bf(av[8 + e]);
    #pragma unroll
    for (int e = 4; e < 8; ++e) a2[e] = 0;                   // k>=24 padding
    union { unsigned int u[4]; bf16x8 v; } B1, B2;
    B1.u[0] = p[0]; B1.u[1] = p[1]; B1.u[2] = p[2]; B1.u[3] = p[3];
    B2.u[0] = p[4]; B2.u[1] = p[5]; B2.u[2] = p[6]; B2.u[3] = p[7];
    f32x16 d = {};
    d = __builtin_amdgcn_mfma_f32_32x32x16_bf16(a1, B1.v, d, 0, 0, 0);
    d = __builtin_amdgcn_mfma_f32_32x32x16_bf16(a2, B2.v, d, 0, 0, 0);
    return d;
  };

  auto CONV = [&](const f32x16& d) {      // D -> next B with exact 2^-dd rescale
    int rb = __builtin_amdgcn_readfirstlane(__float_as_int(d[0]));
    int dd = ((rb >> 23) & 255) - 127;
    E += dd;
    float sc = __int_as_float((127 - dd) << 23);
    #pragma unroll
    for (int r = 0; r < 8; ++r)
      p[r] = (f2bf(d[2 * r + 1] * sc) << 16) | f2bf(d[2 * r] * sc);
  };

  LOADA(b0, 0);
  LOADA(b1, n > 1 ? 1 : 0);
  LOADA(b2, n > 2 ? 2 : 0);
  LOADA(b3, n > 3 ? 3 : 0);
  f32x16 z;
  int s = 0;
  for (;;) {
    z = STEPM(b0);                                   // step s
    if (s + 1 >= n) break;
    CONV(z); { int t = s + 4; LOADA(b0, t < n ? t : n - 1); }
    z = STEPM(b1);                                   // step s+1
    if (s + 2 >= n) break;
    CONV(z); { int t = s + 5; LOADA(b1, t < n ? t : n - 1); }
    z = STEPM(b2);                                   // step s+2
    if (s + 3 >= n) break;
    CONV(z); { int t = s + 6; LOADA(b2, t < n ? t : n - 1); }
    z = STEPM(b3);                                   // step s+3
    if (s + 4 >= n) break;
    CONV(z); { int t = s + 7; LOADA(b3, t < n ? t : n - 1); }
    s += 4;
  }

  // store P = Q^T row m (cols from C/D reg map); regs 12..15 are padding rows
  if (m < KTAG) {
    float* dst = wsP + (size_t)(b * NCHUNK + c) * MAT + m * KTAG;
    float4 v0 = make_float4(z[0], z[1], z[2],  z[3]);
    float4 v1 = make_float4(z[4], z[5], z[6],  z[7]);
    float4 v2 = make_float4(z[8], z[9], z[10], z[11]);
    *(float4*)(dst + 4 * hd)      = v0;    // q-rows 0-3 / 4-7
    *(float4*)(dst + 8 + 4 * hd)  = v1;    // 8-11 / 12-15
    *(float4*)(dst + 16 + 4 * hd) = v2;    // 16-19 / 20-23
  }
  if (lane == 0) wsE[b * NCHUNK + c] = E;
}

// ---------------------------------------------------------------------------
// Phase B: one wave per batch folds chunk matrices into v0 (<=32 matvecs),
// subtracts the batch's gold (chunk partials from wsG + t=0 term), writes
// wsR[b]. No atomics.
// ---------------------------------------------------------------------------
__global__ __launch_bounds__(64) void chainvec_kernel(
    const float* __restrict__ scores, const int* __restrict__ targets,
    const float* __restrict__ wsP, const int* __restrict__ wsE,
    const float* __restrict__ wsG, const int* __restrict__ lengths,
    float* __restrict__ wsR)
{
  __shared__ float tau_s[32];
  volatile float* tau = tau_s;
  const int b = blockIdx.x;
  const int lane = threadIdx.x;
  const int h = lane >> 5;
  const int j = lane & 31;
  const int jj = j < KTAG ? j : KTAG - 1;
  const int len = lengths[b];
  const int nc = (len + 30) >> 5;        // ceil((len-1)/32); live slots = c < nc

  if (lane < KTAG)
    tau[lane] = fexp2(scores[(size_t)b * T_LEN * MAT + START_TAG * KTAG + lane] * LOG2E);

  // gold: chunk partials (only live slots read; dead slots stay poisoned)
  float gv = 0.f;
  if (lane < nc) gv = wsG[b * NCHUNK + lane];
  #pragma unroll
  for (int off = 1; off < 64; off <<= 1) gv += __shfl_xor(gv, off, 64);

  int E = 0;
  float wa[12], wb[12];

  auto LOADV = [&](float (&buf)[12], int c) {
    const float* p = wsP + (size_t)(b * NCHUNK + c) * MAT + (h * 12) * KTAG + jj;
    #pragma unroll
    for (int k = 0; k < 12; ++k) buf[k] = p[k * KTAG];
  };
  auto STEPV = [&](const float (&buf)[12], int c) {
    int ec = wsE[b * NCHUNK + c];
    const float4* tp = (const float4*)((const float*)&tau_s[h * 12]);
    float4 t0 = tp[0], t1 = tp[1], t2 = tp[2];
    float a0 = t0.x * buf[0], a1 = t0.y * buf[1], a2 = t0.z * buf[2], a3 = t0.w * buf[3];
    a0 = fmaf(t1.x, buf[4],  a0); a1 = fmaf(t1.y, buf[5],  a1);
    a2 = fmaf(t1.z, buf[6],  a2); a3 = fmaf(t1.w, buf[7],  a3);
    a0 = fmaf(t2.x, buf[8],  a0); a1 = fmaf(t2.y, buf[9],  a1);
    a2 = fmaf(t2.z, buf[10], a2); a3 = fmaf(t2.w, buf[11], a3);
    float part = (a0 + a1) + (a2 + a3);
    float tot = part + __shfl_xor(part, 32, 64);
    int rb = __builtin_amdgcn_readfirstlane(__float_as_int(tot));
    int d = ((rb >> 23) & 255) - 127;
    E += d + ec;
    float sc = __int_as_float((127 - d) << 23);
    if (lane < KTAG) tau[lane] = tot * sc;
  };

  if (nc > 0) {
    LOADV(wa, 0);
    LOADV(wb, nc > 1 ? 1 : 0);
    int c = 0;
    while (c + 1 < nc) {
      STEPV(wa, c);     { int t = c + 2; LOADV(wa, t < nc ? t : nc - 1); }
      STEPV(wb, c + 1); { int t = c + 3; LOADV(wb, t < nc ? t : nc - 1); }
      c += 2;
    }
    if (c < nc) STEPV(wa, c);
  }

  if (lane == 0) {
    float g0 = scores[(size_t)b * T_LEN * MAT + targets[b * T_LEN]];  // t=0 gold
    float logZ = ((float)E + flog2(tau[END_TAG])) * LN2;
    wsR[b] = logZ - gv - g0;
  }
}

__global__ __launch_bounds__(64) void sum_kernel(
    const float* __restrict__ wsR, float* __restrict__ out)
{
  const int lane = threadIdx.x;
  float v = wsR[lane] + wsR[lane + 64];
  #pragma unroll
  for (int off = 1; off < 64; off <<= 1) v += __shfl_xor(v, off, 64);
  if (lane == 0) out[0] = v * (1.0f / (float)BATCH);
}

// ---------------------------------------------------------------------------
// Fallback path (R2-verified sequential FB) — only if ws_size too small.
// ---------------------------------------------------------------------------
template<int DIR>
__device__ __forceinline__ int run_chain(const float* __restrict__ base, int len, int n,
                                         volatile float* __restrict__ tau,
                                         int lane, int h, int jj)
{
  int E = 0;
  float ref = 1.0f;
  float A[12], B[12], Cb[12];
  auto LOAD = [&](float (&buf)[12], int i) {
    if (DIR == 0) {
      const float* p = base + (size_t)(1 + i) * MAT + h * 12 * KTAG + jj;
      #pragma unroll
      for (int k = 0; k < 12; ++k) buf[k] = p[k * KTAG];
    } else {
      const float4* p = (const float4*)(base + (size_t)(len - 1 - i) * MAT + jj * KTAG + h * 12);
      float4 x = p[0], y = p[1], z = p[2];
      buf[0]=x.x; buf[1]=x.y; buf[2]=x.z; buf[3]=x.w;
      buf[4]=y.x; buf[5]=y.y; buf[6]=y.z; buf[7]=y.w;
      buf[8]=z.x; buf[9]=z.y; buf[10]=z.z; buf[11]=z.w;
    }
  };
  auto STEP = [&](const float (&buf)[12]) {
    int rb = __builtin_amdgcn_readfirstlane(__float_as_int(ref));
    int d = ((rb >> 23) & 255) - 127;
    float sc = __int_as_float((127 - d) << 23);
    E += d;
    float w[12];
    #pragma unroll
    for (int k = 0; k < 12; ++k) w[k] = fexp2(buf[k] * LOG2E);
    const float4* tp = (const float4*)((const float*)&tau[h * 12]);
    float4 t0 = tp[0], t1 = tp[1], t2 = tp[2];
    float a0 = t0.x*w[0], a1 = t0.y*w[1], a2 = t0.z*w[2], a3 = t0.w*w[3];
    a0 = fmaf(t1.x, w[4],  a0); a1 = fmaf(t1.y, w[5],  a1);
    a2 = fmaf(t1.z, w[6],  a2); a3 = fmaf(t1.w, w[7],  a3);
    a0 = fmaf(t2.x, w[8],  a0); a1 = fmaf(t2.y, w[9],  a1);
    a2 = fmaf(t2.z, w[10], a2); a3 = fmaf(t2.w, w[11], a3);
    float part = (a0 + a1) + (a2 + a3);
    float tot = part + __shfl_xor(part, 32, 64);
    float tn = tot * sc;
    if (lane < KTAG) tau[lane] = tn;
    ref = tn;
  };
  if (n > 0) {
    LOAD(A, 0); LOAD(B, n > 1 ? 1 : 0); LOAD(Cb, n > 2 ? 2 : 0);
    int i = 0;
    while (i + 3 <= n) {
      STEP(A);  { int ii = i + 3; LOAD(A,  ii < n ? ii : n - 1); }
      STEP(B);  { int ii = i + 4; LOAD(B,  ii < n ? ii : n - 1); }
      STEP(Cb); { int ii = i + 5; LOAD(Cb, ii < n ? ii : n - 1); }
      i += 3;
    }
    if (i < n)     STEP(A);
    if (i + 1 < n) STEP(B);
  }
  return E;
}

__global__ __launch_bounds__(128) void crf_fb_kernel(
    const float* __restrict__ scores, const int* __restrict__ lengths,
    float* __restrict__ acc)
{
  __shared__ float sm[2][32];
  __shared__ int smE[2];
  const int b = blockIdx.x;
  const int tid = threadIdx.x;
  const int wid = tid >> 6;
  const int lane = tid & 63;
  const int h = lane >> 5;
  const int j = lane & 31;
  const int jj = j < KTAG ? j : KTAG - 1;
  const int len = lengths[b];
  const float* base = scores + (size_t)b * T_LEN * MAT;
  const int m = len >> 1;
  volatile float* tau = sm[wid];
  int E;
  if (wid == 0) {
    if (lane < KTAG) tau[lane] = fexp2(base[START_TAG * KTAG + lane] * LOG2E);
    E = run_chain<0>(base, len, m, tau, lane, h, jj);
  } else {
    if (lane < KTAG) tau[lane] = (lane == END_TAG) ? 1.0f : 0.0f;
    E = run_chain<1>(base, len, len - 1 - m, tau, lane, h, jj);
  }
  if (lane == 0) smE[wid] = E;
  __syncthreads();
  if (wid == 0) {
    float v = (lane < KTAG) ? sm[0][lane] * sm[1][lane] : 0.0f;
    #pragma unroll
    for (int off = 1; off < 32; off <<= 1) v += __shfl_xor(v, off, 64);
    if (lane == 0) {
      float res = ((float)(smE[0] + smE[1]) + flog2(v)) * LN2;
      atomicAdd(acc, res);
    }
  }
}

__global__ __launch_bounds__(256) void gold_kernel(
    const float* __restrict__ scores, const int* __restrict__ targets,
    const int* __restrict__ lengths, float* __restrict__ acc)
{
  const int idx = blockIdx.x * blockDim.x + threadIdx.x;
  const int b = idx >> 10;
  const int t = idx & (T_LEN - 1);
  float v = 0.f;
  if (t < lengths[b]) v = scores[(size_t)idx * MAT + targets[idx]];
  #pragma unroll
  for (int off = 1; off < 64; off <<= 1) v += __shfl_xor(v, off, 64);
  if ((threadIdx.x & 63) == 0) atomicAdd(acc, -v);
}

__global__ void finalize_kernel(const float* __restrict__ acc, float* __restrict__ out) {
  out[0] = acc[0] * (1.0f / (float)BATCH);
}

extern "C" void kernel_launch(void* const* d_in, const int* in_sizes, int n_in,
                              void* d_out, int out_size, void* d_ws, size_t ws_size,
                              hipStream_t stream) {
  const float* scores = (const float*)d_in[0];
  const int* targets  = (const int*)d_in[1];
  const int* lengths  = (const int*)d_in[2];
  float* out = (float*)d_out;

  const size_t pbytes = (size_t)BATCH * NCHUNK * MAT * sizeof(float);
  const size_t ebytes = (size_t)BATCH * NCHUNK * sizeof(int);
  const size_t gbytes = (size_t)BATCH * NCHUNK * sizeof(float);
  const size_t need = pbytes + ebytes + gbytes + BATCH * sizeof(float);

  if (ws_size >= need) {
    float* wsP = (float*)d_ws;
    int*   wsE = (int*)((char*)d_ws + pbytes);
    float* wsG = (float*)((char*)d_ws + pbytes + ebytes);
    float* wsR = (float*)((char*)d_ws + pbytes + ebytes + gbytes);
    chunkprod_kernel<<<BATCH * NCHUNK / 4, 256, 0, stream>>>(scores, targets, lengths,
                                                             wsP, wsE, wsG);
    chainvec_kernel<<<BATCH, 64, 0, stream>>>(scores, targets, wsP, wsE, wsG,
                                              lengths, wsR);
    sum_kernel<<<1, 64, 0, stream>>>(wsR, out);
  } else {
    float* acc = (float*)d_ws;
    hipMemsetAsync(acc, 0, sizeof(float), stream);
    gold_kernel<<<BATCH * T_LEN / 256, 256, 0, stream>>>(scores, targets, lengths, acc);
    crf_fb_kernel<<<BATCH, 128, 0, stream>>>(scores, lengths, acc);
    finalize_kernel<<<1, 1, 0, stream>>>(acc, out);
  }
}

// Round 10
// 63.576 us; speedup vs baseline: 5.6578x; 1.0820x over previous
//
#include <hip/hip_runtime.h>

static constexpr int T_LEN = 1024;
static constexpr int KTAG = 24;
static constexpr int MAT = 576;      // 24*24
static constexpr int START_TAG = 22;
static constexpr int END_TAG = 23;
static constexpr int BATCH = 128;
static constexpr int CHUNK = 32;     // time steps per chunk
static constexpr int NCHUNK = 32;

static constexpr float LOG2E = 1.4426950408889634f;
static constexpr float LN2   = 0.6931471805599453f;

typedef short  bf16x8 __attribute__((ext_vector_type(8)));
typedef float  f32x16 __attribute__((ext_vector_type(16)));

__device__ __forceinline__ float fexp2(float x) { return __builtin_amdgcn_exp2f(x); }
__device__ __forceinline__ float flog2(float x) { return __builtin_amdgcn_logf(x); }

// fp32 -> bf16 bits, round-to-nearest-even (branchless; inputs finite positive).
// NOTE: hand-written v_cvt_pk_bf16_f32 asm was convicted of the R5/R6 NaNs — keep f2bf.
__device__ __forceinline__ unsigned int f2bf(float x) {
  unsigned int u = __float_as_uint(x);
  u += 0x7FFFu + ((u >> 16) & 1u);
  return u >> 16;
}

// ---------------------------------------------------------------------------
// Phase A (MFMA): per-(batch,chunk) wave computes Q = W_{t0+n-1}^T ... W_{t0}^T
// via pairs of mfma_f32_32x32x16_bf16, state Q as B-operand (verified k-slot
// permutation: slot(hd,e) -> k=(e&3)+8*(e>>2)+4*hd, +16 for mfma2).
// bitrev7 wave->(b,c) spread (R8-verified); pack-time exact 2^-dd rescale
// (R8-verified); gold partial -> wsG slot. UNCHANGED from the passing R8 kernel.
// ---------------------------------------------------------------------------
__global__ __launch_bounds__(256) void chunkprod_kernel(
    const float* __restrict__ scores, const int* __restrict__ targets,
    const int* __restrict__ lengths,
    float* __restrict__ wsP, int* __restrict__ wsE, float* __restrict__ wsG)
{
  const int widx = threadIdx.x >> 6;
  const int lane = threadIdx.x & 63;
  const int g = blockIdx.x * 4 + widx;
  const int b = (int)(__brev((unsigned)(g & 127)) >> 25);   // bitrev7: bijection
  const int c = g >> 7;
  const int len = lengths[b];
  const int t0 = 1 + c * CHUNK;
  if (t0 >= len) return;                 // wave-uniform exit; slot never read
  const int n = min(CHUNK, len - t0);
  const int hd = lane >> 5;
  const int m = lane & 31;
  const int mc = m < KTAG ? m : KTAG - 1;   // address clamp for padding rows
  const float* sb = scores + (size_t)b * T_LEN * MAT;

  // fused gold partial: t in [t0, t0+n) -> wsG slot (no atomic)
  {
    float gs = 0.f;
    if (lane < n) {
      int t = t0 + lane;
      gs = sb[(size_t)t * MAT + targets[b * T_LEN + t]];
    }
    #pragma unroll
    for (int off = 1; off < 64; off <<= 1) gs += __shfl_xor(gs, off, 64);
    if (lane == 0) wsG[b * NCHUNK + c] = gs;
  }

  // A-load offsets (dwords) under the k-permutation
  int off1[8], off2[4];
  #pragma unroll
  for (int e = 0; e < 8; ++e) {
    int k = (e & 3) + 8 * (e >> 2) + 4 * hd;         // mfma1 global k
    off1[e] = k * KTAG + mc;
  }
  #pragma unroll
  for (int e = 0; e < 4; ++e) {
    int k = 16 + e + 4 * hd;                         // mfma2 global k (<24)
    off2[e] = k * KTAG + mc;
  }

  float b0[12], b1[12], b2[12], b3[12];
  auto LOADA = [&](float (&buf)[12], int step) {
    const float* pb = sb + (size_t)(t0 + step) * MAT;
    #pragma unroll
    for (int e = 0; e < 8; ++e) buf[e] = pb[off1[e]];
    #pragma unroll
    for (int e = 0; e < 4; ++e) buf[8 + e] = pb[off2[e]];
  };

  // B state: 8 packed uints (2 bf16 each). Init = identity under g().
  unsigned int p[8];
  #pragma unroll
  for (int r = 0; r < 8; ++r) {
    int rlo = ((2 * r) & 3) + 8 * ((2 * r) >> 2) + 4 * hd;  // rows (rlo, rlo+1)
    unsigned int v = 0;
    if (m == rlo)     v |= 0x3F80u;
    if (m == rlo + 1) v |= (0x3F80u << 16);
    p[r] = v;
  }

  int E = 0;

  auto STEPM = [&](const float (&buf)[12]) -> f32x16 {
    float av[12];
    #pragma unroll
    for (int i = 0; i < 12; ++i) av[i] = fexp2(buf[i] * LOG2E);  // loads-only dep
    bf16x8 a1, a2;
    #pragma unroll
    for (int e = 0; e < 8; ++e) a1[e] = (short)f2bf(av[e]);
    #pragma unroll
    for (int e = 0; e < 4; ++e) a2[e] = (short)f2bf(av[8 + e]);
    #pragma unroll
    for (int e = 4; e < 8; ++e) a2[e] = 0;                   // k>=24 padding
    union { unsigned int u[4]; bf16x8 v; } B1, B2;
    B1.u[0] = p[0]; B1.u[1] = p[1]; B1.u[2] = p[2]; B1.u[3] = p[3];
    B2.u[0] = p[4]; B2.u[1] = p[5]; B2.u[2] = p[6]; B2.u[3] = p[7];
    f32x16 d = {};
    d = __builtin_amdgcn_mfma_f32_32x32x16_bf16(a1, B1.v, d, 0, 0, 0);
    d = __builtin_amdgcn_mfma_f32_32x32x16_bf16(a2, B2.v, d, 0, 0, 0);
    return d;
  };

  auto CONV = [&](const f32x16& d) {      // D -> next B with exact 2^-dd rescale
    int rb = __builtin_amdgcn_readfirstlane(__float_as_int(d[0]));
    int dd = ((rb >> 23) & 255) - 127;
    E += dd;
    float sc = __int_as_float((127 - dd) << 23);
    #pragma unroll
    for (int r = 0; r < 8; ++r)
      p[r] = (f2bf(d[2 * r + 1] * sc) << 16) | f2bf(d[2 * r] * sc);
  };

  LOADA(b0, 0);
  LOADA(b1, n > 1 ? 1 : 0);
  LOADA(b2, n > 2 ? 2 : 0);
  LOADA(b3, n > 3 ? 3 : 0);
  f32x16 z;
  int s = 0;
  for (;;) {
    z = STEPM(b0);                                   // step s
    if (s + 1 >= n) break;
    CONV(z); { int t = s + 4; LOADA(b0, t < n ? t : n - 1); }
    z = STEPM(b1);                                   // step s+1
    if (s + 2 >= n) break;
    CONV(z); { int t = s + 5; LOADA(b1, t < n ? t : n - 1); }
    z = STEPM(b2);                                   // step s+2
    if (s + 3 >= n) break;
    CONV(z); { int t = s + 6; LOADA(b2, t < n ? t : n - 1); }
    z = STEPM(b3);                                   // step s+3
    if (s + 4 >= n) break;
    CONV(z); { int t = s + 7; LOADA(b3, t < n ? t : n - 1); }
    s += 4;
  }

  // store P = Q^T row m (cols from C/D reg map); regs 12..15 are padding rows
  if (m < KTAG) {
    float* dst = wsP + (size_t)(b * NCHUNK + c) * MAT + m * KTAG;
    float4 v0 = make_float4(z[0], z[1], z[2],  z[3]);
    float4 v1 = make_float4(z[4], z[5], z[6],  z[7]);
    float4 v2 = make_float4(z[8], z[9], z[10], z[11]);
    *(float4*)(dst + 4 * hd)      = v0;    // q-rows 0-3 / 4-7
    *(float4*)(dst + 8 + 4 * hd)  = v1;    // 8-11 / 12-15
    *(float4*)(dst + 16 + 4 * hd) = v2;    // 16-19 / 20-23
  }
  if (lane == 0) wsE[b * NCHUNK + c] = E;
}

// ---------------------------------------------------------------------------
// Phase B (NEW, MFMA): one wave per batch folds chunk matrices as a matrix
// chain T <- P_c^T * T (same STEPM/CONV machinery, A from wsP, no exp2, no
// LDS). Final: tau_fin[END] = sum_i T[23][i]*tau0[i]; row 23 = z[11] @ hd=1.
// Chunk E-values and gold partials reduced upfront via shuffles.
// ---------------------------------------------------------------------------
__global__ __launch_bounds__(64) void chainmat_kernel(
    const float* __restrict__ scores, const int* __restrict__ targets,
    const float* __restrict__ wsP, const int* __restrict__ wsE,
    const float* __restrict__ wsG, const int* __restrict__ lengths,
    float* __restrict__ wsR)
{
  const int b = blockIdx.x;
  const int lane = threadIdx.x;
  const int hd = lane >> 5;
  const int m = lane & 31;
  const int mc = m < KTAG ? m : KTAG - 1;
  const int len = lengths[b];
  const int nc = (len + 30) >> 5;        // live chunks; dead slots never read
  const float* sb = scores + (size_t)b * T_LEN * MAT;

  // gold: chunk partials + t=0 term
  float gv = 0.f;
  if (lane < nc) gv = wsG[b * NCHUNK + lane];
  #pragma unroll
  for (int off = 1; off < 64; off <<= 1) gv += __shfl_xor(gv, off, 64);
  const float g0 = sb[targets[b * T_LEN]];

  if (nc == 0) {                         // len == 1: logZ = s[0][START][END]
    if (lane == 0) wsR[b] = sb[START_TAG * KTAG + END_TAG] - g0;
    return;
  }

  // total E over live chunks (last chunk's stored E included here;
  // CONVP below only adds the local dd of non-final steps)
  int ev = 0;
  if (lane < nc) ev = wsE[b * NCHUNK + lane];
  #pragma unroll
  for (int off = 1; off < 64; off <<= 1) ev += __shfl_xor(ev, off, 64);
  int E = ev;

  int off1[8], off2[4];
  #pragma unroll
  for (int e = 0; e < 8; ++e) {
    int k = (e & 3) + 8 * (e >> 2) + 4 * hd;
    off1[e] = k * KTAG + mc;
  }
  #pragma unroll
  for (int e = 0; e < 4; ++e) {
    int k = 16 + e + 4 * hd;
    off2[e] = k * KTAG + mc;
  }
  const float* pbase = wsP + (size_t)b * NCHUNK * MAT;

  float b0[12], b1[12];
  auto LOADP = [&](float (&buf)[12], int c) {
    const float* pb = pbase + (size_t)c * MAT;
    #pragma unroll
    for (int e = 0; e < 8; ++e) buf[e] = pb[off1[e]];
    #pragma unroll
    for (int e = 0; e < 4; ++e) buf[8 + e] = pb[off2[e]];
  };

  unsigned int p[8];
  #pragma unroll
  for (int r = 0; r < 8; ++r) {
    int rlo = ((2 * r) & 3) + 8 * ((2 * r) >> 2) + 4 * hd;
    unsigned int v = 0;
    if (m == rlo)     v |= 0x3F80u;
    if (m == rlo + 1) v |= (0x3F80u << 16);
    p[r] = v;
  }

  auto STEPP = [&](const float (&buf)[12]) -> f32x16 {
    bf16x8 a1, a2;
    #pragma unroll
    for (int e = 0; e < 8; ++e) a1[e] = (short)f2bf(buf[e]);
    #pragma unroll
    for (int e = 0; e < 4; ++e) a2[e] = (short)f2bf(buf[8 + e]);
    #pragma unroll
    for (int e = 4; e < 8; ++e) a2[e] = 0;
    union { unsigned int u[4]; bf16x8 v; } B1, B2;
    B1.u[0] = p[0]; B1.u[1] = p[1]; B1.u[2] = p[2]; B1.u[3] = p[3];
    B2.u[0] = p[4]; B2.u[1] = p[5]; B2.u[2] = p[6]; B2.u[3] = p[7];
    f32x16 d = {};
    d = __builtin_amdgcn_mfma_f32_32x32x16_bf16(a1, B1.v, d, 0, 0, 0);
    d = __builtin_amdgcn_mfma_f32_32x32x16_bf16(a2, B2.v, d, 0, 0, 0);
    return d;
  };
  auto CONVP = [&](const f32x16& d) {
    int rb = __builtin_amdgcn_readfirstlane(__float_as_int(d[0]));
    int dd = ((rb >> 23) & 255) - 127;
    E += dd;
    float sc = __int_as_float((127 - dd) << 23);
    #pragma unroll
    for (int r = 0; r < 8; ++r)
      p[r] = (f2bf(d[2 * r + 1] * sc) << 16) | f2bf(d[2 * r] * sc);
  };

  LOADP(b0, 0);
  LOADP(b1, nc > 1 ? 1 : 0);
  f32x16 z;
  int c = 0;
  for (;;) {
    z = STEPP(b0);
    if (c + 1 >= nc) break;
    CONVP(z); { int t = c + 2; LOADP(b0, t < nc ? t : nc - 1); }
    z = STEPP(b1);
    if (c + 2 >= nc) break;
    CONVP(z); { int t = c + 3; LOADP(b1, t < nc ? t : nc - 1); }
    c += 2;
  }

  // tau_fin[END] = sum_i z[11](hd=1, m=i) * tau0[i]
  float tau0 = fexp2(sb[START_TAG * KTAG + mc] * LOG2E);
  float v = (hd == 1 && m < KTAG) ? z[11] * tau0 : 0.f;
  #pragma unroll
  for (int off = 1; off < 64; off <<= 1) v += __shfl_xor(v, off, 64);
  if (lane == 0) {
    float logZ = ((float)E + flog2(v)) * LN2;
    wsR[b] = logZ - gv - g0;
  }
}

__global__ __launch_bounds__(64) void sum_kernel(
    const float* __restrict__ wsR, float* __restrict__ out)
{
  const int lane = threadIdx.x;
  float v = wsR[lane] + wsR[lane + 64];
  #pragma unroll
  for (int off = 1; off < 64; off <<= 1) v += __shfl_xor(v, off, 64);
  if (lane == 0) out[0] = v * (1.0f / (float)BATCH);
}

// ---------------------------------------------------------------------------
// Fallback path (R2-verified sequential FB) — only if ws_size too small.
// ---------------------------------------------------------------------------
template<int DIR>
__device__ __forceinline__ int run_chain(const float* __restrict__ base, int len, int n,
                                         volatile float* __restrict__ tau,
                                         int lane, int h, int jj)
{
  int E = 0;
  float ref = 1.0f;
  float A[12], B[12], Cb[12];
  auto LOAD = [&](float (&buf)[12], int i) {
    if (DIR == 0) {
      const float* p = base + (size_t)(1 + i) * MAT + h * 12 * KTAG + jj;
      #pragma unroll
      for (int k = 0; k < 12; ++k) buf[k] = p[k * KTAG];
    } else {
      const float4* p = (const float4*)(base + (size_t)(len - 1 - i) * MAT + jj * KTAG + h * 12);
      float4 x = p[0], y = p[1], z = p[2];
      buf[0]=x.x; buf[1]=x.y; buf[2]=x.z; buf[3]=x.w;
      buf[4]=y.x; buf[5]=y.y; buf[6]=y.z; buf[7]=y.w;
      buf[8]=z.x; buf[9]=z.y; buf[10]=z.z; buf[11]=z.w;
    }
  };
  auto STEP = [&](const float (&buf)[12]) {
    int rb = __builtin_amdgcn_readfirstlane(__float_as_int(ref));
    int d = ((rb >> 23) & 255) - 127;
    float sc = __int_as_float((127 - d) << 23);
    E += d;
    float w[12];
    #pragma unroll
    for (int k = 0; k < 12; ++k) w[k] = fexp2(buf[k] * LOG2E);
    const float4* tp = (const float4*)((const float*)&tau[h * 12]);
    float4 t0 = tp[0], t1 = tp[1], t2 = tp[2];
    float a0 = t0.x*w[0], a1 = t0.y*w[1], a2 = t0.z*w[2], a3 = t0.w*w[3];
    a0 = fmaf(t1.x, w[4],  a0); a1 = fmaf(t1.y, w[5],  a1);
    a2 = fmaf(t1.z, w[6],  a2); a3 = fmaf(t1.w, w[7],  a3);
    a0 = fmaf(t2.x, w[8],  a0); a1 = fmaf(t2.y, w[9],  a1);
    a2 = fmaf(t2.z, w[10], a2); a3 = fmaf(t2.w, w[11], a3);
    float part = (a0 + a1) + (a2 + a3);
    float tot = part + __shfl_xor(part, 32, 64);
    float tn = tot * sc;
    if (lane < KTAG) tau[lane] = tn;
    ref = tn;
  };
  if (n > 0) {
    LOAD(A, 0); LOAD(B, n > 1 ? 1 : 0); LOAD(Cb, n > 2 ? 2 : 0);
    int i = 0;
    while (i + 3 <= n) {
      STEP(A);  { int ii = i + 3; LOAD(A,  ii < n ? ii : n - 1); }
      STEP(B);  { int ii = i + 4; LOAD(B,  ii < n ? ii : n - 1); }
      STEP(Cb); { int ii = i + 5; LOAD(Cb, ii < n ? ii : n - 1); }
      i += 3;
    }
    if (i < n)     STEP(A);
    if (i + 1 < n) STEP(B);
  }
  return E;
}

__global__ __launch_bounds__(128) void crf_fb_kernel(
    const float* __restrict__ scores, const int* __restrict__ lengths,
    float* __restrict__ acc)
{
  __shared__ float sm[2][32];
  __shared__ int smE[2];
  const int b = blockIdx.x;
  const int tid = threadIdx.x;
  const int wid = tid >> 6;
  const int lane = tid & 63;
  const int h = lane >> 5;
  const int j = lane & 31;
  const int jj = j < KTAG ? j : KTAG - 1;
  const int len = lengths[b];
  const float* base = scores + (size_t)b * T_LEN * MAT;
  const int m = len >> 1;
  volatile float* tau = sm[wid];
  int E;
  if (wid == 0) {
    if (lane < KTAG) tau[lane] = fexp2(base[START_TAG * KTAG + lane] * LOG2E);
    E = run_chain<0>(base, len, m, tau, lane, h, jj);
  } else {
    if (lane < KTAG) tau[lane] = (lane == END_TAG) ? 1.0f : 0.0f;
    E = run_chain<1>(base, len, len - 1 - m, tau, lane, h, jj);
  }
  if (lane == 0) smE[wid] = E;
  __syncthreads();
  if (wid == 0) {
    float v = (lane < KTAG) ? sm[0][lane] * sm[1][lane] : 0.0f;
    #pragma unroll
    for (int off = 1; off < 32; off <<= 1) v += __shfl_xor(v, off, 64);
    if (lane == 0) {
      float res = ((float)(smE[0] + smE[1]) + flog2(v)) * LN2;
      atomicAdd(acc, res);
    }
  }
}

__global__ __launch_bounds__(256) void gold_kernel(
    const float* __restrict__ scores, const int* __restrict__ targets,
    const int* __restrict__ lengths, float* __restrict__ acc)
{
  const int idx = blockIdx.x * blockDim.x + threadIdx.x;
  const int b = idx >> 10;
  const int t = idx & (T_LEN - 1);
  float v = 0.f;
  if (t < lengths[b]) v = scores[(size_t)idx * MAT + targets[idx]];
  #pragma unroll
  for (int off = 1; off < 64; off <<= 1) v += __shfl_xor(v, off, 64);
  if ((threadIdx.x & 63) == 0) atomicAdd(acc, -v);
}

__global__ void finalize_kernel(const float* __restrict__ acc, float* __restrict__ out) {
  out[0] = acc[0] * (1.0f / (float)BATCH);
}

extern "C" void kernel_launch(void* const* d_in, const int* in_sizes, int n_in,
                              void* d_out, int out_size, void* d_ws, size_t ws_size,
                              hipStream_t stream) {
  const float* scores = (const float*)d_in[0];
  const int* targets  = (const int*)d_in[1];
  const int* lengths  = (const int*)d_in[2];
  float* out = (float*)d_out;

  const size_t pbytes = (size_t)BATCH * NCHUNK * MAT * sizeof(float);
  const size_t ebytes = (size_t)BATCH * NCHUNK * sizeof(int);
  const size_t gbytes = (size_t)BATCH * NCHUNK * sizeof(float);
  const size_t need = pbytes + ebytes + gbytes + BATCH * sizeof(float);

  if (ws_size >= need) {
    float* wsP = (float*)d_ws;
    int*   wsE = (int*)((char*)d_ws + pbytes);
    float* wsG = (float*)((char*)d_ws + pbytes + ebytes);
    float* wsR = (float*)((char*)d_ws + pbytes + ebytes + gbytes);
    chunkprod_kernel<<<BATCH * NCHUNK / 4, 256, 0, stream>>>(scores, targets, lengths,
                                                             wsP, wsE, wsG);
    chainmat_kernel<<<BATCH, 64, 0, stream>>>(scores, targets, wsP, wsE, wsG,
                                              lengths, wsR);
    sum_kernel<<<1, 64, 0, stream>>>(wsR, out);
  } else {
    float* acc = (float*)d_ws;
    hipMemsetAsync(acc, 0, sizeof(float), stream);
    gold_kernel<<<BATCH * T_LEN / 256, 256, 0, stream>>>(scores, targets, lengths, acc);
    crf_fb_kernel<<<BATCH, 128, 0, stream>>>(scores, lengths, acc);
    finalize_kernel<<<1, 1, 0, stream>>>(acc, out);
  }
}

// Round 11
// 55.140 us; speedup vs baseline: 6.5233x; 1.1530x over previous
//
#include <hip/hip_runtime.h>

static constexpr int T_LEN = 1024;
static constexpr int KTAG = 24;
static constexpr int MAT = 576;      // 24*24
static constexpr int START_TAG = 22;
static constexpr int END_TAG = 23;
static constexpr int BATCH = 128;
static constexpr int CHUNK = 32;     // time steps per chunk
static constexpr int NCHUNK = 32;

static constexpr float LOG2E = 1.4426950408889634f;
static constexpr float LN2   = 0.6931471805599453f;

typedef short  bf16x8 __attribute__((ext_vector_type(8)));
typedef float  f32x16 __attribute__((ext_vector_type(16)));

__device__ __forceinline__ float fexp2(float x) { return __builtin_amdgcn_exp2f(x); }
__device__ __forceinline__ float flog2(float x) { return __builtin_amdgcn_logf(x); }

// fp32 -> bf16 bits, round-to-nearest-even (branchless; inputs finite positive).
// NOTE: hand-written v_cvt_pk_bf16_f32 asm was convicted of the R5/R6 NaNs — keep f2bf.
__device__ __forceinline__ unsigned int f2bf(float x) {
  unsigned int u = __float_as_uint(x);
  u += 0x7FFFu + ((u >> 16) & 1u);
  return u >> 16;
}

// ---------------------------------------------------------------------------
// Phase A (MFMA): per-(batch,chunk) wave computes Q = W_{t0+n-1}^T ... W_{t0}^T
// via pairs of mfma_f32_32x32x16_bf16, state Q as B-operand (verified k-slot
// permutation: slot(hd,e) -> k=(e&3)+8*(e>>2)+4*hd, +16 for mfma2).
// SCHEDULE (R10): ANTITHETIC PAIRS. lengths are sorted, so len[b]+len[127-b]
// ~= 1025; pairing item (b,c) with (127-b,31-c) makes each wave-pair's step
// count ~32 constant, so EVERY block does ~64 steps regardless of block->CU
// mapping. anti=0 covers c<16, anti=1 covers c>=16 -> bijection over (b,c).
// Pack-time exact 2^-dd rescale + wsG gold slots: unchanged (R8/R9-verified).
// ---------------------------------------------------------------------------
__global__ __launch_bounds__(256) void chunkprod_kernel(
    const float* __restrict__ scores, const int* __restrict__ targets,
    const int* __restrict__ lengths,
    float* __restrict__ wsP, int* __restrict__ wsE, float* __restrict__ wsG)
{
  const int widx = threadIdx.x >> 6;
  const int lane = threadIdx.x & 63;
  const int i = blockIdx.x * 4 + widx;
  const int pr = i >> 1;                 // pair id in [0,2048)
  const int anti = i & 1;
  const int b0 = pr >> 4;                // [0,128)
  const int c0 = pr & 15;                // [0,16)
  const int b = anti ? (127 - b0) : b0;
  const int c = anti ? (31 - c0) : c0;
  const int len = lengths[b];
  const int t0 = 1 + c * CHUNK;
  if (t0 >= len) return;                 // wave-uniform exit; slot never read
  const int n = min(CHUNK, len - t0);
  const int hd = lane >> 5;
  const int m = lane & 31;
  const int mc = m < KTAG ? m : KTAG - 1;   // address clamp for padding rows
  const float* sb = scores + (size_t)b * T_LEN * MAT;

  // fused gold partial: t in [t0, t0+n) -> wsG slot (no atomic)
  {
    float gs = 0.f;
    if (lane < n) {
      int t = t0 + lane;
      gs = sb[(size_t)t * MAT + targets[b * T_LEN + t]];
    }
    #pragma unroll
    for (int off = 1; off < 64; off <<= 1) gs += __shfl_xor(gs, off, 64);
    if (lane == 0) wsG[b * NCHUNK + c] = gs;
  }

  // A-load offsets (dwords) under the k-permutation
  int off1[8], off2[4];
  #pragma unroll
  for (int e = 0; e < 8; ++e) {
    int k = (e & 3) + 8 * (e >> 2) + 4 * hd;         // mfma1 global k
    off1[e] = k * KTAG + mc;
  }
  #pragma unroll
  for (int e = 0; e < 4; ++e) {
    int k = 16 + e + 4 * hd;                         // mfma2 global k (<24)
    off2[e] = k * KTAG + mc;
  }

  float b0r[12], b1r[12], b2r[12], b3r[12];
  auto LOADA = [&](float (&buf)[12], int step) {
    const float* pb = sb + (size_t)(t0 + step) * MAT;
    #pragma unroll
    for (int e = 0; e < 8; ++e) buf[e] = pb[off1[e]];
    #pragma unroll
    for (int e = 0; e < 4; ++e) buf[8 + e] = pb[off2[e]];
  };

  // B state: 8 packed uints (2 bf16 each). Init = identity under g().
  unsigned int p[8];
  #pragma unroll
  for (int r = 0; r < 8; ++r) {
    int rlo = ((2 * r) & 3) + 8 * ((2 * r) >> 2) + 4 * hd;  // rows (rlo, rlo+1)
    unsigned int v = 0;
    if (m == rlo)     v |= 0x3F80u;
    if (m == rlo + 1) v |= (0x3F80u << 16);
    p[r] = v;
  }

  int E = 0;

  auto STEPM = [&](const float (&buf)[12]) -> f32x16 {
    float av[12];
    #pragma unroll
    for (int i2 = 0; i2 < 12; ++i2) av[i2] = fexp2(buf[i2] * LOG2E);  // loads-only dep
    bf16x8 a1, a2;
    #pragma unroll
    for (int e = 0; e < 8; ++e) a1[e] = (short)f2bf(av[e]);
    #pragma unroll
    for (int e = 0; e < 4; ++e) a2[e] = (short)f2bf(av[8 + e]);
    #pragma unroll
    for (int e = 4; e < 8; ++e) a2[e] = 0;                   // k>=24 padding
    union { unsigned int u[4]; bf16x8 v; } B1, B2;
    B1.u[0] = p[0]; B1.u[1] = p[1]; B1.u[2] = p[2]; B1.u[3] = p[3];
    B2.u[0] = p[4]; B2.u[1] = p[5]; B2.u[2] = p[6]; B2.u[3] = p[7];
    f32x16 d = {};
    d = __builtin_amdgcn_mfma_f32_32x32x16_bf16(a1, B1.v, d, 0, 0, 0);
    d = __builtin_amdgcn_mfma_f32_32x32x16_bf16(a2, B2.v, d, 0, 0, 0);
    return d;
  };

  auto CONV = [&](const f32x16& d) {      // D -> next B with exact 2^-dd rescale
    int rb = __builtin_amdgcn_readfirstlane(__float_as_int(d[0]));
    int dd = ((rb >> 23) & 255) - 127;
    E += dd;
    float sc = __int_as_float((127 - dd) << 23);
    #pragma unroll
    for (int r = 0; r < 8; ++r)
      p[r] = (f2bf(d[2 * r + 1] * sc) << 16) | f2bf(d[2 * r] * sc);
  };

  LOADA(b0r, 0);
  LOADA(b1r, n > 1 ? 1 : 0);
  LOADA(b2r, n > 2 ? 2 : 0);
  LOADA(b3r, n > 3 ? 3 : 0);
  f32x16 z;
  int s = 0;
  for (;;) {
    z = STEPM(b0r);                                  // step s
    if (s + 1 >= n) break;
    CONV(z); { int t = s + 4; LOADA(b0r, t < n ? t : n - 1); }
    z = STEPM(b1r);                                  // step s+1
    if (s + 2 >= n) break;
    CONV(z); { int t = s + 5; LOADA(b1r, t < n ? t : n - 1); }
    z = STEPM(b2r);                                  // step s+2
    if (s + 3 >= n) break;
    CONV(z); { int t = s + 6; LOADA(b2r, t < n ? t : n - 1); }
    z = STEPM(b3r);                                  // step s+3
    if (s + 4 >= n) break;
    CONV(z); { int t = s + 7; LOADA(b3r, t < n ? t : n - 1); }
    s += 4;
  }

  // store P = Q^T row m (cols from C/D reg map); regs 12..15 are padding rows
  if (m < KTAG) {
    float* dst = wsP + (size_t)(b * NCHUNK + c) * MAT + m * KTAG;
    float4 v0 = make_float4(z[0], z[1], z[2],  z[3]);
    float4 v1 = make_float4(z[4], z[5], z[6],  z[7]);
    float4 v2 = make_float4(z[8], z[9], z[10], z[11]);
    *(float4*)(dst + 4 * hd)      = v0;    // q-rows 0-3 / 4-7
    *(float4*)(dst + 8 + 4 * hd)  = v1;    // 8-11 / 12-15
    *(float4*)(dst + 16 + 4 * hd) = v2;    // 16-19 / 20-23
  }
  if (lane == 0) wsE[b * NCHUNK + c] = E;
}

// ---------------------------------------------------------------------------
// Phase B (MFMA): one wave per batch folds chunk matrices as a matrix chain
// T <- P_c^T * T (same machinery, A from wsP, no exp2, no LDS). Final:
// tau_fin[END] = sum_i T[23][i]*tau0[i]; row 23 = z[11] @ hd=1. UNCHANGED (R9).
// ---------------------------------------------------------------------------
__global__ __launch_bounds__(64) void chainmat_kernel(
    const float* __restrict__ scores, const int* __restrict__ targets,
    const float* __restrict__ wsP, const int* __restrict__ wsE,
    const float* __restrict__ wsG, const int* __restrict__ lengths,
    float* __restrict__ wsR)
{
  const int b = blockIdx.x;
  const int lane = threadIdx.x;
  const int hd = lane >> 5;
  const int m = lane & 31;
  const int mc = m < KTAG ? m : KTAG - 1;
  const int len = lengths[b];
  const int nc = (len + 30) >> 5;        // live chunks; dead slots never read
  const float* sb = scores + (size_t)b * T_LEN * MAT;

  // gold: chunk partials + t=0 term
  float gv = 0.f;
  if (lane < nc) gv = wsG[b * NCHUNK + lane];
  #pragma unroll
  for (int off = 1; off < 64; off <<= 1) gv += __shfl_xor(gv, off, 64);
  const float g0 = sb[targets[b * T_LEN]];

  if (nc == 0) {                         // len == 1: logZ = s[0][START][END]
    if (lane == 0) wsR[b] = sb[START_TAG * KTAG + END_TAG] - g0;
    return;
  }

  int ev = 0;
  if (lane < nc) ev = wsE[b * NCHUNK + lane];
  #pragma unroll
  for (int off = 1; off < 64; off <<= 1) ev += __shfl_xor(ev, off, 64);
  int E = ev;

  int off1[8], off2[4];
  #pragma unroll
  for (int e = 0; e < 8; ++e) {
    int k = (e & 3) + 8 * (e >> 2) + 4 * hd;
    off1[e] = k * KTAG + mc;
  }
  #pragma unroll
  for (int e = 0; e < 4; ++e) {
    int k = 16 + e + 4 * hd;
    off2[e] = k * KTAG + mc;
  }
  const float* pbase = wsP + (size_t)b * NCHUNK * MAT;

  float b0[12], b1[12];
  auto LOADP = [&](float (&buf)[12], int c) {
    const float* pb = pbase + (size_t)c * MAT;
    #pragma unroll
    for (int e = 0; e < 8; ++e) buf[e] = pb[off1[e]];
    #pragma unroll
    for (int e = 0; e < 4; ++e) buf[8 + e] = pb[off2[e]];
  };

  unsigned int p[8];
  #pragma unroll
  for (int r = 0; r < 8; ++r) {
    int rlo = ((2 * r) & 3) + 8 * ((2 * r) >> 2) + 4 * hd;
    unsigned int v = 0;
    if (m == rlo)     v |= 0x3F80u;
    if (m == rlo + 1) v |= (0x3F80u << 16);
    p[r] = v;
  }

  auto STEPP = [&](const float (&buf)[12]) -> f32x16 {
    bf16x8 a1, a2;
    #pragma unroll
    for (int e = 0; e < 8; ++e) a1[e] = (short)f2bf(buf[e]);
    #pragma unroll
    for (int e = 0; e < 4; ++e) a2[e] = (short)f2bf(buf[8 + e]);
    #pragma unroll
    for (int e = 4; e < 8; ++e) a2[e] = 0;
    union { unsigned int u[4]; bf16x8 v; } B1, B2;
    B1.u[0] = p[0]; B1.u[1] = p[1]; B1.u[2] = p[2]; B1.u[3] = p[3];
    B2.u[0] = p[4]; B2.u[1] = p[5]; B2.u[2] = p[6]; B2.u[3] = p[7];
    f32x16 d = {};
    d = __builtin_amdgcn_mfma_f32_32x32x16_bf16(a1, B1.v, d, 0, 0, 0);
    d = __builtin_amdgcn_mfma_f32_32x32x16_bf16(a2, B2.v, d, 0, 0, 0);
    return d;
  };
  auto CONVP = [&](const f32x16& d) {
    int rb = __builtin_amdgcn_readfirstlane(__float_as_int(d[0]));
    int dd = ((rb >> 23) & 255) - 127;
    E += dd;
    float sc = __int_as_float((127 - dd) << 23);
    #pragma unroll
    for (int r = 0; r < 8; ++r)
      p[r] = (f2bf(d[2 * r + 1] * sc) << 16) | f2bf(d[2 * r] * sc);
  };

  LOADP(b0, 0);
  LOADP(b1, nc > 1 ? 1 : 0);
  f32x16 z;
  int c = 0;
  for (;;) {
    z = STEPP(b0);
    if (c + 1 >= nc) break;
    CONVP(z); { int t = c + 2; LOADP(b0, t < nc ? t : nc - 1); }
    z = STEPP(b1);
    if (c + 2 >= nc) break;
    CONVP(z); { int t = c + 3; LOADP(b1, t < nc ? t : nc - 1); }
    c += 2;
  }

  // tau_fin[END] = sum_i z[11](hd=1, m=i) * tau0[i]
  float tau0 = fexp2(sb[START_TAG * KTAG + mc] * LOG2E);
  float v = (hd == 1 && m < KTAG) ? z[11] * tau0 : 0.f;
  #pragma unroll
  for (int off = 1; off < 64; off <<= 1) v += __shfl_xor(v, off, 64);
  if (lane == 0) {
    float logZ = ((float)E + flog2(v)) * LN2;
    wsR[b] = logZ - gv - g0;
  }
}

__global__ __launch_bounds__(64) void sum_kernel(
    const float* __restrict__ wsR, float* __restrict__ out)
{
  const int lane = threadIdx.x;
  float v = wsR[lane] + wsR[lane + 64];
  #pragma unroll
  for (int off = 1; off < 64; off <<= 1) v += __shfl_xor(v, off, 64);
  if (lane == 0) out[0] = v * (1.0f / (float)BATCH);
}

// ---------------------------------------------------------------------------
// Fallback path (R2-verified sequential FB) — only if ws_size too small.
// ---------------------------------------------------------------------------
template<int DIR>
__device__ __forceinline__ int run_chain(const float* __restrict__ base, int len, int n,
                                         volatile float* __restrict__ tau,
                                         int lane, int h, int jj)
{
  int E = 0;
  float ref = 1.0f;
  float A[12], B[12], Cb[12];
  auto LOAD = [&](float (&buf)[12], int i) {
    if (DIR == 0) {
      const float* p = base + (size_t)(1 + i) * MAT + h * 12 * KTAG + jj;
      #pragma unroll
      for (int k = 0; k < 12; ++k) buf[k] = p[k * KTAG];
    } else {
      const float4* p = (const float4*)(base + (size_t)(len - 1 - i) * MAT + jj * KTAG + h * 12);
      float4 x = p[0], y = p[1], z = p[2];
      buf[0]=x.x; buf[1]=x.y; buf[2]=x.z; buf[3]=x.w;
      buf[4]=y.x; buf[5]=y.y; buf[6]=y.z; buf[7]=y.w;
      buf[8]=z.x; buf[9]=z.y; buf[10]=z.z; buf[11]=z.w;
    }
  };
  auto STEP = [&](const float (&buf)[12]) {
    int rb = __builtin_amdgcn_readfirstlane(__float_as_int(ref));
    int d = ((rb >> 23) & 255) - 127;
    float sc = __int_as_float((127 - d) << 23);
    E += d;
    float w[12];
    #pragma unroll
    for (int k = 0; k < 12; ++k) w[k] = fexp2(buf[k] * LOG2E);
    const float4* tp = (const float4*)((const float*)&tau[h * 12]);
    float4 t0 = tp[0], t1 = tp[1], t2 = tp[2];
    float a0 = t0.x*w[0], a1 = t0.y*w[1], a2 = t0.z*w[2], a3 = t0.w*w[3];
    a0 = fmaf(t1.x, w[4],  a0); a1 = fmaf(t1.y, w[5],  a1);
    a2 = fmaf(t1.z, w[6],  a2); a3 = fmaf(t1.w, w[7],  a3);
    a0 = fmaf(t2.x, w[8],  a0); a1 = fmaf(t2.y, w[9],  a1);
    a2 = fmaf(t2.z, w[10], a2); a3 = fmaf(t2.w, w[11], a3);
    float part = (a0 + a1) + (a2 + a3);
    float tot = part + __shfl_xor(part, 32, 64);
    float tn = tot * sc;
    if (lane < KTAG) tau[lane] = tn;
    ref = tn;
  };
  if (n > 0) {
    LOAD(A, 0); LOAD(B, n > 1 ? 1 : 0); LOAD(Cb, n > 2 ? 2 : 0);
    int i = 0;
    while (i + 3 <= n) {
      STEP(A);  { int ii = i + 3; LOAD(A,  ii < n ? ii : n - 1); }
      STEP(B);  { int ii = i + 4; LOAD(B,  ii < n ? ii : n - 1); }
      STEP(Cb); { int ii = i + 5; LOAD(Cb, ii < n ? ii : n - 1); }
      i += 3;
    }
    if (i < n)     STEP(A);
    if (i + 1 < n) STEP(B);
  }
  return E;
}

__global__ __launch_bounds__(128) void crf_fb_kernel(
    const float* __restrict__ scores, const int* __restrict__ lengths,
    float* __restrict__ acc)
{
  __shared__ float sm[2][32];
  __shared__ int smE[2];
  const int b = blockIdx.x;
  const int tid = threadIdx.x;
  const int wid = tid >> 6;
  const int lane = tid & 63;
  const int h = lane >> 5;
  const int j = lane & 31;
  const int jj = j < KTAG ? j : KTAG - 1;
  const int len = lengths[b];
  const float* base = scores + (size_t)b * T_LEN * MAT;
  const int m = len >> 1;
  volatile float* tau = sm[wid];
  int E;
  if (wid == 0) {
    if (lane < KTAG) tau[lane] = fexp2(base[START_TAG * KTAG + lane] * LOG2E);
    E = run_chain<0>(base, len, m, tau, lane, h, jj);
  } else {
    if (lane < KTAG) tau[lane] = (lane == END_TAG) ? 1.0f : 0.0f;
    E = run_chain<1>(base, len, len - 1 - m, tau, lane, h, jj);
  }
  if (lane == 0) smE[wid] = E;
  __syncthreads();
  if (wid == 0) {
    float v = (lane < KTAG) ? sm[0][lane] * sm[1][lane] : 0.0f;
    #pragma unroll
    for (int off = 1; off < 32; off <<= 1) v += __shfl_xor(v, off, 64);
    if (lane == 0) {
      float res = ((float)(smE[0] + smE[1]) + flog2(v)) * LN2;
      atomicAdd(acc, res);
    }
  }
}

__global__ __launch_bounds__(256) void gold_kernel(
    const float* __restrict__ scores, const int* __restrict__ targets,
    const int* __restrict__ lengths, float* __restrict__ acc)
{
  const int idx = blockIdx.x * blockDim.x + threadIdx.x;
  const int b = idx >> 10;
  const int t = idx & (T_LEN - 1);
  float v = 0.f;
  if (t < lengths[b]) v = scores[(size_t)idx * MAT + targets[idx]];
  #pragma unroll
  for (int off = 1; off < 64; off <<= 1) v += __shfl_xor(v, off, 64);
  if ((threadIdx.x & 63) == 0) atomicAdd(acc, -v);
}

__global__ void finalize_kernel(const float* __restrict__ acc, float* __restrict__ out) {
  out[0] = acc[0] * (1.0f / (float)BATCH);
}

extern "C" void kernel_launch(void* const* d_in, const int* in_sizes, int n_in,
                              void* d_out, int out_size, void* d_ws, size_t ws_size,
                              hipStream_t stream) {
  const float* scores = (const float*)d_in[0];
  const int* targets  = (const int*)d_in[1];
  const int* lengths  = (const int*)d_in[2];
  float* out = (float*)d_out;

  const size_t pbytes = (size_t)BATCH * NCHUNK * MAT * sizeof(float);
  const size_t ebytes = (size_t)BATCH * NCHUNK * sizeof(int);
  const size_t gbytes = (size_t)BATCH * NCHUNK * sizeof(float);
  const size_t need = pbytes + ebytes + gbytes + BATCH * sizeof(float);

  if (ws_size >= need) {
    float* wsP = (float*)d_ws;
    int*   wsE = (int*)((char*)d_ws + pbytes);
    float* wsG = (float*)((char*)d_ws + pbytes + ebytes);
    float* wsR = (float*)((char*)d_ws + pbytes + ebytes + gbytes);
    chunkprod_kernel<<<BATCH * NCHUNK / 4, 256, 0, stream>>>(scores, targets, lengths,
                                                             wsP, wsE, wsG);
    chainmat_kernel<<<BATCH, 64, 0, stream>>>(scores, targets, wsP, wsE, wsG,
                                              lengths, wsR);
    sum_kernel<<<1, 64, 0, stream>>>(wsR, out);
  } else {
    float* acc = (float*)d_ws;
    hipMemsetAsync(acc, 0, sizeof(float), stream);
    gold_kernel<<<BATCH * T_LEN / 256, 256, 0, stream>>>(scores, targets, lengths, acc);
    crf_fb_kernel<<<BATCH, 128, 0, stream>>>(scores, lengths, acc);
    finalize_kernel<<<1, 1, 0, stream>>>(acc, out);
  }
}